// Round 3
// baseline (8169.254 us; speedup 1.0000x reference)
//
#include <hip/hip_runtime.h>
#include <cmath>

#define BN 4
#define HF 256
#define WF 448
#define HWF (HF*WF)   // 114688
#define GCHUNKS 64
#define GPIX (HWF/GCHUNKS)   // 1792

#define TW 32
#define TH 8
#define CI_CHUNK 40

__device__ __forceinline__ float clampf(float v, float lo, float hi) {
    return fminf(fmaxf(v, lo), hi);
}

// ---- gate conv partials ----
__global__ void gate_conv_kernel(const float* __restrict__ x,
                                 const float* __restrict__ wr,
                                 const float* __restrict__ br,
                                 double* __restrict__ partial) {
    int co    = blockIdx.x >> 6;
    int chunk = blockIdx.x & 63;
    __shared__ float wsh[54];
    if (threadIdx.x < 54) wsh[threadIdx.x] = wr[co*54 + threadIdx.x];
    __syncthreads();
    float bias = br[co];
    float facc = 0.0f;
    int p0 = chunk * GPIX;
    for (int k = threadIdx.x; k < GPIX; k += blockDim.x) {
        int p = p0 + k;
        int y = p / WF, xx = p % WF;
        float s = bias;
        #pragma unroll
        for (int ci = 0; ci < 6; ++ci) {
            const float* ip = x + (size_t)ci*HWF;
            const float* wp = wsh + ci*9;
            #pragma unroll
            for (int ky = 0; ky < 3; ++ky) {
                int iy = y + ky - 1;
                if ((unsigned)iy >= HF) continue;
                #pragma unroll
                for (int kx = 0; kx < 3; ++kx) {
                    int ix = xx + kx - 1;
                    if ((unsigned)ix >= WF) continue;
                    s += ip[iy*WF + ix] * wp[ky*3+kx];
                }
            }
        }
        facc += fmaxf(s, 0.0f);
    }
    __shared__ double red[256];
    red[threadIdx.x] = (double)facc;
    __syncthreads();
    for (int off = 128; off > 0; off >>= 1) {
        if ((int)threadIdx.x < off) red[threadIdx.x] += red[threadIdx.x + off];
        __syncthreads();
    }
    if (threadIdx.x == 0) partial[co*GCHUNKS + chunk] = red[0];
}

// ---- gate FC ----
__global__ void gate_fc_kernel(const double* __restrict__ partial,
                               const float* __restrict__ wl,
                               const float* __restrict__ bl,
                               float* __restrict__ g) {
    __shared__ double rm[32];
    __shared__ double v[9];
    int i = threadIdx.x;
    if (i < 32) {
        double s = 0.0;
        for (int k = 0; k < GCHUNKS; ++k) s += partial[i*GCHUNKS + k];
        rm[i] = s / (double)HWF;
    }
    __syncthreads();
    if (i < 9) {
        double t = (double)bl[i];
        for (int c = 0; c < 32; ++c) t += rm[c] * (double)wl[i*32+c];
        v[i] = 1.0 / (1.0 + exp(-t));
    }
    __syncthreads();
    if (i == 0) {
        double s = 0.0;
        for (int k = 0; k < 9; ++k) s += v[k];
        for (int k = 0; k < 9; ++k) {
            double vn = v[k] / (s + 1e-6) * 4.5;
            vn = vn < 0.0 ? 0.0 : (vn > 1.0 ? 1.0 : vn);
            g[k] = (float)rint(vn);
        }
    }
}

// ---- weight transpose: wcb [36][co80][ci80][9] -> wT [36][ci80][co80][9] ----
__global__ void wtrans_kernel(const float* __restrict__ wcb, float* __restrict__ wT) {
    int idx = blockIdx.x*blockDim.x + threadIdx.x;
    if (idx >= 36*80*80*9) return;
    int tap = idx % 9;
    int ci  = (idx / 9) % 80;
    int co  = (idx / (9*80)) % 80;
    int conv= idx / (9*80*80);
    wT[(((size_t)conv*80 + ci)*80 + co)*9 + tap] = wcb[idx];
}

// ---- init ----
__global__ void init_kernel(const float* __restrict__ x,
                            float* __restrict__ flow, float* __restrict__ mask,
                            float* __restrict__ w0, float* __restrict__ w1) {
    int idx = blockIdx.x * blockDim.x + threadIdx.x;
    if (idx < BN*4*HWF) flow[idx] = 0.0f;
    if (idx < BN*HWF)   mask[idx] = 0.0f;
    if (idx < BN*3*HWF) {
        int b = idx / (3*HWF), r = idx % (3*HWF);
        w0[idx] = x[(size_t)b*6*HWF + r];
        w1[idx] = x[(size_t)b*6*HWF + 3*HWF + r];
    }
}

// ---- prepare ----
__global__ void prepare_kernel(const float* __restrict__ x,
                               const float* __restrict__ w0buf, const float* __restrict__ w1buf,
                               const float* __restrict__ mask, const float* __restrict__ flow,
                               const float* __restrict__ g, int gi,
                               float* __restrict__ t, int s, int sh, int sw) {
    if (g[gi] == 0.0f) return;
    int idx = blockIdx.x * blockDim.x + threadIdx.x;
    int total = BN*17*sh*sw;
    if (idx >= total) return;
    int ox = idx % sw;
    int oy = (idx / sw) % sh;
    int c  = (idx / (sw*sh)) % 17;
    int b  = idx / (sw*sh*17);
    const float* src; float mult = 1.0f;
    if (c < 6)        src = x + ((size_t)b*6 + c)*HWF;
    else if (c < 9)   src = w0buf + ((size_t)b*3 + (c-6))*HWF;
    else if (c < 12)  src = w1buf + ((size_t)b*3 + (c-9))*HWF;
    else if (c == 12) src = mask + (size_t)b*HWF;
    else { src = flow + ((size_t)b*4 + (c-13))*HWF; mult = 1.0f / (float)s; }
    float val;
    if (s == 1) {
        val = src[oy*WF + ox];
    } else {
        int nt = 2*s;
        float posy = (oy + 0.5f)*(float)s - 0.5f;
        float posx = (ox + 0.5f)*(float)s - 0.5f;
        int jy0 = s*oy - s/2;
        int jx0 = s*ox - s/2;
        float wy[8], wx[8], sy = 0.f, sx = 0.f;
        for (int k = 0; k < nt; ++k) {
            int j = jy0 + k;
            float ww = 1.0f - fabsf((float)j - posy)/(float)s;
            if (j < 0 || j >= HF) ww = 0.f;
            wy[k] = ww; sy += ww;
        }
        for (int k = 0; k < nt; ++k) {
            int j = jx0 + k;
            float ww = 1.0f - fabsf((float)j - posx)/(float)s;
            if (j < 0 || j >= WF) ww = 0.f;
            wx[k] = ww; sx += ww;
        }
        float acc = 0.f;
        for (int a = 0; a < nt; ++a) {
            if (wy[a] == 0.f) continue;
            const float* rp = src + (jy0 + a)*WF;
            float rowacc = 0.f;
            for (int bb = 0; bb < nt; ++bb) {
                if (wx[bb] == 0.f) continue;
                rowacc += wx[bb] * rp[jx0 + bb];
            }
            acc += wy[a] * rowacc;
        }
        val = acc / (sy * sx);
    }
    t[idx] = val * mult;
}

// ---- generic 3x3 conv (used for 17->40 s2 and 40->80 s2) ----
__global__ void conv3x3_kernel(const float* __restrict__ in,
                               const float* __restrict__ w,
                               const float* __restrict__ bias,
                               const float* __restrict__ resid,
                               const float* __restrict__ g, int gi,
                               float* __restrict__ out,
                               int Cin, int Cout, int Hin, int Win,
                               int Hout, int Wout, int stride, int pad,
                               int do_relu) {
    if (g[gi] == 0.0f) return;
    int idx = blockIdx.x * blockDim.x + threadIdx.x;
    int total = BN*Cout*Hout*Wout;
    if (idx >= total) return;
    int xx = idx % Wout;
    int y  = (idx / Wout) % Hout;
    int co = (idx / (Wout*Hout)) % Cout;
    int b  = idx / (Wout*Hout*Cout);
    float acc = bias[co];
    const float* ib = in + (size_t)b*Cin*Hin*Win;
    const float* wb = w + (size_t)co*Cin*9;
    for (int ci = 0; ci < Cin; ++ci) {
        const float* ip = ib + (size_t)ci*Hin*Win;
        const float* wp = wb + ci*9;
        #pragma unroll
        for (int ky = 0; ky < 3; ++ky) {
            int iy = y*stride + ky - pad;
            if ((unsigned)iy >= (unsigned)Hin) continue;
            const float* rp = ip + iy*Win;
            #pragma unroll
            for (int kx = 0; kx < 3; ++kx) {
                int ix = xx*stride + kx - pad;
                if ((unsigned)ix >= (unsigned)Win) continue;
                acc += rp[ix] * wp[ky*3+kx];
            }
        }
    }
    if (do_relu) acc = fmaxf(acc, 0.0f);
    if (resid) acc += resid[idx];
    out[idx] = acc;
}

// ---- specialized 80->80 s1 p1 conv, register-blocked, LDS-tiled ----
// grid: ntx*nty*2*B blocks, 256 threads; each block: 40 co over 32x8 tile
__global__ __launch_bounds__(256, 2)
void conv80_kernel(const float* __restrict__ in,   // [B][80][H][W]
                   const float* __restrict__ wT,   // [80ci][80co][9]
                   const float* __restrict__ bias, // [80]
                   const float* __restrict__ resid,
                   const float* __restrict__ g, int gi,
                   float* __restrict__ out,
                   int H, int W) {
    if (g[gi] == 0.0f) return;
    int ntx = (W + TW - 1) / TW;
    int nty = H / TH;
    int bx = blockIdx.x % ntx;
    int by = (blockIdx.x / ntx) % nty;
    int half = (blockIdx.x / (ntx*nty)) & 1;
    int b = blockIdx.x / (ntx*nty*2);
    int x0 = bx*TW, y0 = by*TH;

    __shared__ float lds[CI_CHUNK][TH+2][TW+2];   // 40*10*34*4B = 54.4KB

    int tid = threadIdx.x;
    int px = tid & 31, py = tid >> 5;
    int ox = x0 + px, oy = y0 + py;
    bool act = ox < W;

    float acc[40];
    #pragma unroll
    for (int k = 0; k < 40; ++k) acc[k] = 0.0f;

    const float* inb = in + (size_t)b*80*H*W;

    for (int cc = 0; cc < 2; ++cc) {
        int ci0 = cc*CI_CHUNK;
        __syncthreads();
        for (int idx = tid; idx < CI_CHUNK*(TH+2)*(TW+2); idx += 256) {
            int rx = idx % (TW+2);
            int ry = (idx / (TW+2)) % (TH+2);
            int ci = idx / ((TW+2)*(TH+2));
            int gx = x0 + rx - 1, gy = y0 + ry - 1;
            float v = 0.0f;
            if ((unsigned)gx < (unsigned)W && (unsigned)gy < (unsigned)H)
                v = inb[((size_t)(ci0+ci)*H + gy)*W + gx];
            lds[ci][ry][rx] = v;
        }
        __syncthreads();
        for (int ci = 0; ci < CI_CHUNK; ++ci) {
            float v[9];
            #pragma unroll
            for (int dy = 0; dy < 3; ++dy)
                #pragma unroll
                for (int dx = 0; dx < 3; ++dx)
                    v[dy*3+dx] = lds[ci][py+dy][px+dx];
            const float* wp = wT + ((size_t)(ci0+ci)*80 + half*40)*9;
            #pragma unroll
            for (int co = 0; co < 40; ++co) {
                #pragma unroll
                for (int t9 = 0; t9 < 9; ++t9)
                    acc[co] = fmaf(v[t9], wp[co*9+t9], acc[co]);
            }
        }
    }
    if (act) {
        size_t base = ((size_t)b*80 + half*40)*H*W + (size_t)oy*W + ox;
        #pragma unroll
        for (int co = 0; co < 40; ++co) {
            float r = fmaxf(acc[co] + bias[half*40+co], 0.0f);
            if (resid) r += resid[base + (size_t)co*H*W];
            out[base + (size_t)co*H*W] = r;
        }
    }
}

// ---- transposed conv 4x4 s2 ----
__global__ void deconv_kernel(const float* __restrict__ t,
                              const float* __restrict__ wl,
                              const float* __restrict__ bl,
                              const float* __restrict__ g, int gi,
                              float* __restrict__ out,
                              int h2, int w2) {
    if (g[gi] == 0.0f) return;
    int ho = 2*h2, wo = 2*w2;
    int idx = blockIdx.x * blockDim.x + threadIdx.x;
    int total = BN*5*ho*wo;
    if (idx >= total) return;
    int xx = idx % wo;
    int y  = (idx / wo) % ho;
    int o  = (idx / (wo*ho)) % 5;
    int b  = idx / (wo*ho*5);
    float acc = bl[o];
    int p = y & 1, q = xx & 1;
    const float* tb = t + (size_t)b*80*h2*w2;
    for (int dy = 0; dy < 2; ++dy) {
        int ky = p + 2*dy;
        int iy = (y + ky - 2) >> 1;
        if ((unsigned)iy >= (unsigned)h2) continue;
        for (int dx = 0; dx < 2; ++dx) {
            int kx = q + 2*dx;
            int ix = (xx + kx - 2) >> 1;
            if ((unsigned)ix >= (unsigned)w2) continue;
            const float* tp = tb + iy*w2 + ix;
            const float* wp = wl + (size_t)o*80*16 + ky*4 + kx;
            for (int i = 0; i < 80; ++i)
                acc += tp[(size_t)i*h2*w2] * wp[i*16];
        }
    }
    out[idx] = acc;
}

// ---- bilinear upsample + gated accumulate ----
__global__ void upsample_accum_kernel(const float* __restrict__ tmp,
                                      const float* __restrict__ g, int gi,
                                      float* __restrict__ flow, float* __restrict__ mask,
                                      int h, int w, int f, float fdscale) {
    float gg = g[gi];
    if (gg == 0.0f) return;
    int idx = blockIdx.x * blockDim.x + threadIdx.x;
    int total = BN*5*HWF;
    if (idx >= total) return;
    int xx = idx % WF;
    int y  = (idx / WF) % HF;
    int c  = (idx / HWF) % 5;
    int b  = idx / (HWF*5);
    float posy = (y + 0.5f)/(float)f - 0.5f;
    float posx = (xx + 0.5f)/(float)f - 0.5f;
    float y0f = floorf(posy), x0f = floorf(posx);
    int jy0 = (int)y0f, jx0 = (int)x0f;
    float fy = posy - y0f, fx = posx - x0f;
    int jy1 = min(jy0 + 1, h-1), jx1 = min(jx0 + 1, w-1);
    jy0 = max(jy0, 0); jx0 = max(jx0, 0);
    const float* tp = tmp + ((size_t)(b*5 + c))*h*w;
    float v00 = tp[jy0*w + jx0], v01 = tp[jy0*w + jx1];
    float v10 = tp[jy1*w + jx0], v11 = tp[jy1*w + jx1];
    float val = v00*(1-fx)*(1-fy) + v01*fx*(1-fy) + v10*(1-fx)*fy + v11*fx*fy;
    int p2 = y*WF + xx;
    if (c < 4) flow[((size_t)b*4 + c)*HWF + p2] += val * fdscale * gg;
    else       mask[(size_t)b*HWF + p2] += val * gg;
}

// ---- warp ----
__global__ void warp_kernel(const float* __restrict__ x,
                            const float* __restrict__ flow,
                            const float* __restrict__ g, int gi,
                            float* __restrict__ w0, float* __restrict__ w1) {
    if (g[gi] == 0.0f) return;
    int idx = blockIdx.x*blockDim.x + threadIdx.x;
    int total = BN*6*HWF;
    if (idx >= total) return;
    int p  = idx % HWF;
    int c  = (idx / HWF) % 6;
    int b  = idx / (HWF*6);
    int xx = p % WF, y = p / WF;
    int which = (c >= 3) ? 1 : 0;
    const float* fl = flow + ((size_t)b*4 + which*2)*HWF;
    float sx = clampf((float)xx + fl[p], 0.f, (float)(WF-1));
    float sy = clampf((float)y  + fl[HWF + p], 0.f, (float)(HF-1));
    float x0f = floorf(sx), y0f = floorf(sy);
    int x0 = (int)x0f, y0 = (int)y0f;
    int x1 = min(x0 + 1, WF - 1), y1 = min(y0 + 1, HF - 1);
    float wx = sx - x0f, wy = sy - y0f;
    const float* im = x + ((size_t)b*6 + c)*HWF;
    float v00 = im[y0*WF + x0], v01 = im[y0*WF + x1];
    float v10 = im[y1*WF + x0], v11 = im[y1*WF + x1];
    float val = v00*(1-wx)*(1-wy) + v01*wx*(1-wy) + v10*(1-wx)*wy + v11*wx*wy;
    float* dst = which ? w1 : w0;
    dst[((size_t)b*3 + (c - which*3))*HWF + p] = val;
}

// ---- final blend ----
__global__ void final_kernel(const float* __restrict__ w0, const float* __restrict__ w1,
                             const float* __restrict__ mask, float* __restrict__ outp) {
    int idx = blockIdx.x*blockDim.x + threadIdx.x;
    if (idx >= BN*3*HWF) return;
    int p = idx % HWF;
    int b = idx / (3*HWF);
    float m = 1.0f / (1.0f + expf(-mask[(size_t)b*HWF + p]));
    float val = w0[idx]*m + w1[idx]*(1.0f - m);
    outp[idx] = clampf(val, 0.0f, 1.0f);
}

extern "C" void kernel_launch(void* const* d_in, const int* in_sizes, int n_in,
                              void* d_out, int out_size, void* d_ws, size_t ws_size,
                              hipStream_t stream) {
    const float* x     = (const float*)d_in[0];
    const float* wr    = (const float*)d_in[1];
    const float* br    = (const float*)d_in[2];
    const float* wl    = (const float*)d_in[3];
    const float* bl    = (const float*)d_in[4];
    const float* w0a   = (const float*)d_in[5];
    const float* b0a   = (const float*)d_in[6];
    const float* w0b   = (const float*)d_in[7];
    const float* b0b   = (const float*)d_in[8];
    const float* wcb   = (const float*)d_in[9];
    const float* bcb   = (const float*)d_in[10];
    const float* wlast = (const float*)d_in[11];
    const float* blast = (const float*)d_in[12];

    float* ws      = (float*)d_ws;
    double* partial = (double*)d_ws;             // 32*GCHUNKS doubles = 4096 floats
    float* g       = ws + 4096;                  // 16 floats
    size_t off = 4112;
    float* flow = ws + off; off += (size_t)BN*4*HWF;
    float* mask = ws + off; off += (size_t)BN*1*HWF;
    float* wb0  = ws + off; off += (size_t)BN*3*HWF;
    float* wb1  = ws + off; off += (size_t)BN*3*HWF;
    float* tin  = ws + off; off += (size_t)BN*17*HWF;
    float* t0   = ws + off; off += (size_t)BN*40*(HF/2)*(WF/2);
    float* t1   = ws + off; off += (size_t)BN*80*(HF/4)*(WF/4);
    float* ra   = ws + off; off += (size_t)BN*80*(HF/4)*(WF/4);
    float* rb   = ws + off; off += (size_t)BN*80*(HF/4)*(WF/4);
    float* tmpb = ws + off; off += (size_t)BN*5*(HF/2)*(WF/2);
    float* wT   = ws + off; off += (size_t)36*80*80*9;   // 2,073,600 floats

    gate_conv_kernel<<<32*GCHUNKS, 256, 0, stream>>>(x, wr, br, partial);
    gate_fc_kernel<<<1, 64, 0, stream>>>(partial, wl, bl, g);
    {
        int n = 36*80*80*9;
        wtrans_kernel<<<(n+255)/256, 256, 0, stream>>>(wcb, wT);
    }
    {
        int n = BN*4*HWF;
        init_kernel<<<(n+255)/256, 256, 0, stream>>>(x, flow, mask, wb0, wb1);
    }
    const int SC[9] = {4,4,4,2,2,2,1,1,1};
    for (int i = 0; i < 9; ++i) {
        int s = SC[i];
        int sh = HF/s, sw = WF/s;
        int h = sh/2, w = sw/2;
        int h2 = h/2, w2 = w/2;
        {
            int n = BN*17*sh*sw;
            prepare_kernel<<<(n+255)/256,256,0,stream>>>(x, wb0, wb1, mask, flow, g, i, tin, s, sh, sw);
        }
        {
            int n = BN*40*h*w;
            conv3x3_kernel<<<(n+255)/256,256,0,stream>>>(tin, w0a + (size_t)i*40*17*9, b0a + i*40,
                nullptr, g, i, t0, 17, 40, sh, sw, h, w, 2, 0, 1);
        }
        {
            int n = BN*80*h2*w2;
            conv3x3_kernel<<<(n+255)/256,256,0,stream>>>(t0, w0b + (size_t)i*80*40*9, b0b + i*80,
                nullptr, g, i, t1, 40, 80, h, w, h2, w2, 2, 0, 1);
        }
        const float* cin = t1;
        float* cout = ra;
        int ntx = (w2 + TW - 1) / TW;
        int nty = h2 / TH;
        int nblk = ntx * nty * 2 * BN;
        for (int j = 0; j < 4; ++j) {
            const float* res = (j == 3) ? t1 : nullptr;
            conv80_kernel<<<nblk, 256, 0, stream>>>(cin,
                wT + ((size_t)i*4 + j)*80*80*9, bcb + ((size_t)i*4 + j)*80,
                res, g, i, cout, h2, w2);
            cin = cout;
            cout = (cout == ra) ? rb : ra;
        }
        {
            int n = BN*5*h*w;
            deconv_kernel<<<(n+255)/256,256,0,stream>>>(cin, wlast + (size_t)i*5*80*16, blast + i*5,
                g, i, tmpb, h2, w2);
        }
        {
            int n = BN*5*HWF;
            upsample_accum_kernel<<<(n+255)/256,256,0,stream>>>(tmpb, g, i, flow, mask, h, w, 2*s, (float)(2*s));
        }
        {
            int n = BN*6*HWF;
            warp_kernel<<<(n+255)/256,256,0,stream>>>(x, flow, g, i, wb0, wb1);
        }
    }
    {
        int n = BN*3*HWF;
        final_kernel<<<(n+255)/256,256,0,stream>>>(wb0, wb1, mask, (float*)d_out);
    }
}

// Round 4
// 3285.141 us; speedup vs baseline: 2.4867x; 2.4867x over previous
//
#include <hip/hip_runtime.h>
#include <cmath>

#define BN 4
#define HF 256
#define WF 448
#define HWF (HF*WF)   // 114688
#define GCHUNKS 64
#define GPIX (HWF/GCHUNKS)   // 1792

#define TW 32
#define TH 8

__device__ __forceinline__ float clampf(float v, float lo, float hi) {
    return fminf(fmaxf(v, lo), hi);
}

// ---- gate conv partials ----
__global__ void gate_conv_kernel(const float* __restrict__ x,
                                 const float* __restrict__ wr,
                                 const float* __restrict__ br,
                                 double* __restrict__ partial) {
    int co    = blockIdx.x >> 6;
    int chunk = blockIdx.x & 63;
    __shared__ float wsh[54];
    if (threadIdx.x < 54) wsh[threadIdx.x] = wr[co*54 + threadIdx.x];
    __syncthreads();
    float bias = br[co];
    float facc = 0.0f;
    int p0 = chunk * GPIX;
    for (int k = threadIdx.x; k < GPIX; k += blockDim.x) {
        int p = p0 + k;
        int y = p / WF, xx = p % WF;
        float s = bias;
        #pragma unroll
        for (int ci = 0; ci < 6; ++ci) {
            const float* ip = x + (size_t)ci*HWF;
            const float* wp = wsh + ci*9;
            #pragma unroll
            for (int ky = 0; ky < 3; ++ky) {
                int iy = y + ky - 1;
                if ((unsigned)iy >= HF) continue;
                #pragma unroll
                for (int kx = 0; kx < 3; ++kx) {
                    int ix = xx + kx - 1;
                    if ((unsigned)ix >= WF) continue;
                    s += ip[iy*WF + ix] * wp[ky*3+kx];
                }
            }
        }
        facc += fmaxf(s, 0.0f);
    }
    __shared__ double red[256];
    red[threadIdx.x] = (double)facc;
    __syncthreads();
    for (int off = 128; off > 0; off >>= 1) {
        if ((int)threadIdx.x < off) red[threadIdx.x] += red[threadIdx.x + off];
        __syncthreads();
    }
    if (threadIdx.x == 0) partial[co*GCHUNKS + chunk] = red[0];
}

// ---- gate FC ----
__global__ void gate_fc_kernel(const double* __restrict__ partial,
                               const float* __restrict__ wl,
                               const float* __restrict__ bl,
                               float* __restrict__ g) {
    __shared__ double rm[32];
    __shared__ double v[9];
    int i = threadIdx.x;
    if (i < 32) {
        double s = 0.0;
        for (int k = 0; k < GCHUNKS; ++k) s += partial[i*GCHUNKS + k];
        rm[i] = s / (double)HWF;
    }
    __syncthreads();
    if (i < 9) {
        double t = (double)bl[i];
        for (int c = 0; c < 32; ++c) t += rm[c] * (double)wl[i*32+c];
        v[i] = 1.0 / (1.0 + exp(-t));
    }
    __syncthreads();
    if (i == 0) {
        double s = 0.0;
        for (int k = 0; k < 9; ++k) s += v[k];
        for (int k = 0; k < 9; ++k) {
            double vn = v[k] / (s + 1e-6) * 4.5;
            vn = vn < 0.0 ? 0.0 : (vn > 1.0 ? 1.0 : vn);
            g[k] = (float)rint(vn);
        }
    }
}

// ---- generic weight transpose: w [nconv][Cout][Cin][9] -> wT [nconv][Cin][9][Cout] ----
__global__ void wtrans_kernel(const float* __restrict__ w, float* __restrict__ wT,
                              int nconv, int Cout, int Cin) {
    int idx = blockIdx.x*blockDim.x + threadIdx.x;
    int total = nconv*Cout*Cin*9;
    if (idx >= total) return;
    int t9 = idx % 9;
    int ci = (idx/9) % Cin;
    int co = (idx/(9*Cin)) % Cout;
    int cv = idx/(9*Cin*Cout);
    wT[(((size_t)cv*Cin+ci)*9+t9)*Cout + co] = w[idx];
}

// ---- init ----
__global__ void init_kernel(const float* __restrict__ x,
                            float* __restrict__ flow, float* __restrict__ mask,
                            float* __restrict__ w0, float* __restrict__ w1) {
    int idx = blockIdx.x * blockDim.x + threadIdx.x;
    if (idx < BN*4*HWF) flow[idx] = 0.0f;
    if (idx < BN*HWF)   mask[idx] = 0.0f;
    if (idx < BN*3*HWF) {
        int b = idx / (3*HWF), r = idx % (3*HWF);
        w0[idx] = x[(size_t)b*6*HWF + r];
        w1[idx] = x[(size_t)b*6*HWF + 3*HWF + r];
    }
}

// ---- prepare ----
__global__ void prepare_kernel(const float* __restrict__ x,
                               const float* __restrict__ w0buf, const float* __restrict__ w1buf,
                               const float* __restrict__ mask, const float* __restrict__ flow,
                               const float* __restrict__ g, int gi,
                               float* __restrict__ t, int s, int sh, int sw) {
    if (g[gi] == 0.0f) return;
    int idx = blockIdx.x * blockDim.x + threadIdx.x;
    int total = BN*17*sh*sw;
    if (idx >= total) return;
    int ox = idx % sw;
    int oy = (idx / sw) % sh;
    int c  = (idx / (sw*sh)) % 17;
    int b  = idx / (sw*sh*17);
    const float* src; float mult = 1.0f;
    if (c < 6)        src = x + ((size_t)b*6 + c)*HWF;
    else if (c < 9)   src = w0buf + ((size_t)b*3 + (c-6))*HWF;
    else if (c < 12)  src = w1buf + ((size_t)b*3 + (c-9))*HWF;
    else if (c == 12) src = mask + (size_t)b*HWF;
    else { src = flow + ((size_t)b*4 + (c-13))*HWF; mult = 1.0f / (float)s; }
    float val;
    if (s == 1) {
        val = src[oy*WF + ox];
    } else {
        int nt = 2*s;
        float posy = (oy + 0.5f)*(float)s - 0.5f;
        float posx = (ox + 0.5f)*(float)s - 0.5f;
        int jy0 = s*oy - s/2;
        int jx0 = s*ox - s/2;
        float wy[8], wx[8], sy = 0.f, sx = 0.f;
        for (int k = 0; k < nt; ++k) {
            int j = jy0 + k;
            float ww = 1.0f - fabsf((float)j - posy)/(float)s;
            if (j < 0 || j >= HF) ww = 0.f;
            wy[k] = ww; sy += ww;
        }
        for (int k = 0; k < nt; ++k) {
            int j = jx0 + k;
            float ww = 1.0f - fabsf((float)j - posx)/(float)s;
            if (j < 0 || j >= WF) ww = 0.f;
            wx[k] = ww; sx += ww;
        }
        float acc = 0.f;
        for (int a = 0; a < nt; ++a) {
            if (wy[a] == 0.f) continue;
            const float* rp = src + (jy0 + a)*WF;
            float rowacc = 0.f;
            for (int bb = 0; bb < nt; ++bb) {
                if (wx[bb] == 0.f) continue;
                rowacc += wx[bb] * rp[jx0 + bb];
            }
            acc += wy[a] * rowacc;
        }
        val = acc / (sy * sx);
    }
    t[idx] = val * mult;
}

// ---- LDS-tiled 3x3 conv, 20 co per block, input+weights staged in LDS ----
// STRIDE=1: pad 1; STRIDE=2: pad (0,1) SAME. relu always; optional residual add.
template<int STRIDE>
__global__ __launch_bounds__(256, 4)
void conv_lds_kernel(const float* __restrict__ in,
                     const float* __restrict__ wT,   // [Cin][9][Cout]
                     const float* __restrict__ bias,
                     const float* __restrict__ resid,
                     const float* __restrict__ g, int gi,
                     float* __restrict__ out,
                     int Cin, int Cout, int Hin, int Win, int Hout, int Wout) {
    if (g[gi] == 0.0f) return;
    constexpr int CI  = (STRIDE==1) ? 10 : 5;
    constexpr int IW  = (STRIDE==1) ? (TW+2) : (2*TW+3);
    constexpr int IH  = (STRIDE==1) ? (TH+2) : (2*TH+3);
    constexpr int PAD = (STRIDE==1) ? 1 : 0;
    __shared__ float sIn[CI*IH*IW];
    __shared__ float sW[CI*9*20];

    int ntx = (Wout + TW-1)/TW;
    int nty = (Hout + TH-1)/TH;
    int nq  = Cout/20;
    int bx  = blockIdx.x % ntx;
    int tmp = blockIdx.x / ntx;
    int by  = tmp % nty; tmp /= nty;
    int q   = tmp % nq;
    int b   = tmp / nq;
    int x0 = bx*TW, y0 = by*TH;
    int coB = q*20;

    int tid = threadIdx.x;
    int px = tid & 31, py = tid >> 5;
    int ox = x0+px, oy = y0+py;
    bool act = (ox < Wout) && (oy < Hout);

    float acc[20];
    #pragma unroll
    for (int k=0;k<20;++k) acc[k]=0.f;

    const float* inb = in + (size_t)b*Cin*Hin*Win;

    for (int ci0 = 0; ci0 < Cin; ci0 += CI) {
        int cs = min(CI, Cin-ci0);
        __syncthreads();
        int nel = cs*IH*IW;
        for (int idx = tid; idx < nel; idx += 256) {
            int rx = idx % IW;
            int ry = (idx / IW) % IH;
            int ci = idx / (IW*IH);
            int gx = x0*STRIDE + rx - PAD;
            int gy = y0*STRIDE + ry - PAD;
            float v = 0.f;
            if ((unsigned)gx < (unsigned)Win && (unsigned)gy < (unsigned)Hin)
                v = inb[((size_t)(ci0+ci)*Hin + gy)*Win + gx];
            sIn[(ci*IH+ry)*IW+rx] = v;
        }
        int nw = cs*180;
        for (int idx = tid; idx < nw; idx += 256) {
            int co = idx % 20;
            int t9 = (idx/20) % 9;
            int ci = idx / 180;
            sW[idx] = wT[((size_t)(ci0+ci)*9 + t9)*Cout + coB + co];
        }
        __syncthreads();
        for (int ci = 0; ci < cs; ++ci) {
            float v[9];
            #pragma unroll
            for (int dy=0; dy<3; ++dy)
                #pragma unroll
                for (int dx=0; dx<3; ++dx)
                    v[dy*3+dx] = sIn[(ci*IH + py*STRIDE+dy)*IW + px*STRIDE+dx];
            const float* wp = sW + ci*180;
            #pragma unroll
            for (int t9=0; t9<9; ++t9) {
                #pragma unroll
                for (int c4=0; c4<5; ++c4) {
                    const float4 wv = *(const float4*)(wp + t9*20 + c4*4);
                    acc[c4*4+0] = fmaf(v[t9], wv.x, acc[c4*4+0]);
                    acc[c4*4+1] = fmaf(v[t9], wv.y, acc[c4*4+1]);
                    acc[c4*4+2] = fmaf(v[t9], wv.z, acc[c4*4+2]);
                    acc[c4*4+3] = fmaf(v[t9], wv.w, acc[c4*4+3]);
                }
            }
        }
    }
    if (act) {
        size_t chw = (size_t)Hout*Wout;
        size_t base = ((size_t)b*Cout + coB)*chw + (size_t)oy*Wout + ox;
        #pragma unroll
        for (int co=0; co<20; ++co) {
            float r = fmaxf(acc[co] + bias[coB+co], 0.0f);
            if (resid) r += resid[base + co*chw];
            out[base + co*chw] = r;
        }
    }
}

// ---- transposed conv 4x4 s2 ----
__global__ void deconv_kernel(const float* __restrict__ t,
                              const float* __restrict__ wl,
                              const float* __restrict__ bl,
                              const float* __restrict__ g, int gi,
                              float* __restrict__ out,
                              int h2, int w2) {
    if (g[gi] == 0.0f) return;
    int ho = 2*h2, wo = 2*w2;
    int idx = blockIdx.x * blockDim.x + threadIdx.x;
    int total = BN*5*ho*wo;
    if (idx >= total) return;
    int xx = idx % wo;
    int y  = (idx / wo) % ho;
    int o  = (idx / (wo*ho)) % 5;
    int b  = idx / (wo*ho*5);
    float acc = bl[o];
    int p = y & 1, q = xx & 1;
    const float* tb = t + (size_t)b*80*h2*w2;
    for (int dy = 0; dy < 2; ++dy) {
        int ky = p + 2*dy;
        int iy = (y + ky - 2) >> 1;
        if ((unsigned)iy >= (unsigned)h2) continue;
        for (int dx = 0; dx < 2; ++dx) {
            int kx = q + 2*dx;
            int ix = (xx + kx - 2) >> 1;
            if ((unsigned)ix >= (unsigned)w2) continue;
            const float* tp = tb + iy*w2 + ix;
            const float* wp = wl + (size_t)o*80*16 + ky*4 + kx;
            for (int i = 0; i < 80; ++i)
                acc += tp[(size_t)i*h2*w2] * wp[i*16];
        }
    }
    out[idx] = acc;
}

// ---- bilinear upsample + gated accumulate ----
__global__ void upsample_accum_kernel(const float* __restrict__ tmp,
                                      const float* __restrict__ g, int gi,
                                      float* __restrict__ flow, float* __restrict__ mask,
                                      int h, int w, int f, float fdscale) {
    float gg = g[gi];
    if (gg == 0.0f) return;
    int idx = blockIdx.x * blockDim.x + threadIdx.x;
    int total = BN*5*HWF;
    if (idx >= total) return;
    int xx = idx % WF;
    int y  = (idx / WF) % HF;
    int c  = (idx / HWF) % 5;
    int b  = idx / (HWF*5);
    float posy = (y + 0.5f)/(float)f - 0.5f;
    float posx = (xx + 0.5f)/(float)f - 0.5f;
    float y0f = floorf(posy), x0f = floorf(posx);
    int jy0 = (int)y0f, jx0 = (int)x0f;
    float fy = posy - y0f, fx = posx - x0f;
    int jy1 = min(jy0 + 1, h-1), jx1 = min(jx0 + 1, w-1);
    jy0 = max(jy0, 0); jx0 = max(jx0, 0);
    const float* tp = tmp + ((size_t)(b*5 + c))*h*w;
    float v00 = tp[jy0*w + jx0], v01 = tp[jy0*w + jx1];
    float v10 = tp[jy1*w + jx0], v11 = tp[jy1*w + jx1];
    float val = v00*(1-fx)*(1-fy) + v01*fx*(1-fy) + v10*(1-fx)*fy + v11*fx*fy;
    int p2 = y*WF + xx;
    if (c < 4) flow[((size_t)b*4 + c)*HWF + p2] += val * fdscale * gg;
    else       mask[(size_t)b*HWF + p2] += val * gg;
}

// ---- warp ----
__global__ void warp_kernel(const float* __restrict__ x,
                            const float* __restrict__ flow,
                            const float* __restrict__ g, int gi,
                            float* __restrict__ w0, float* __restrict__ w1) {
    if (g[gi] == 0.0f) return;
    int idx = blockIdx.x*blockDim.x + threadIdx.x;
    int total = BN*6*HWF;
    if (idx >= total) return;
    int p  = idx % HWF;
    int c  = (idx / HWF) % 6;
    int b  = idx / (HWF*6);
    int xx = p % WF, y = p / WF;
    int which = (c >= 3) ? 1 : 0;
    const float* fl = flow + ((size_t)b*4 + which*2)*HWF;
    float sx = clampf((float)xx + fl[p], 0.f, (float)(WF-1));
    float sy = clampf((float)y  + fl[HWF + p], 0.f, (float)(HF-1));
    float x0f = floorf(sx), y0f = floorf(sy);
    int x0 = (int)x0f, y0 = (int)y0f;
    int x1 = min(x0 + 1, WF - 1), y1 = min(y0 + 1, HF - 1);
    float wx = sx - x0f, wy = sy - y0f;
    const float* im = x + ((size_t)b*6 + c)*HWF;
    float v00 = im[y0*WF + x0], v01 = im[y0*WF + x1];
    float v10 = im[y1*WF + x0], v11 = im[y1*WF + x1];
    float val = v00*(1-wx)*(1-wy) + v01*wx*(1-wy) + v10*(1-wx)*wy + v11*wx*wy;
    float* dst = which ? w1 : w0;
    dst[((size_t)b*3 + (c - which*3))*HWF + p] = val;
}

// ---- final blend ----
__global__ void final_kernel(const float* __restrict__ w0, const float* __restrict__ w1,
                             const float* __restrict__ mask, float* __restrict__ outp) {
    int idx = blockIdx.x*blockDim.x + threadIdx.x;
    if (idx >= BN*3*HWF) return;
    int p = idx % HWF;
    int b = idx / (3*HWF);
    float m = 1.0f / (1.0f + expf(-mask[(size_t)b*HWF + p]));
    float val = w0[idx]*m + w1[idx]*(1.0f - m);
    outp[idx] = clampf(val, 0.0f, 1.0f);
}

static inline int conv_grid(int Hout, int Wout, int Cout) {
    int ntx = (Wout + TW-1)/TW;
    int nty = (Hout + TH-1)/TH;
    return ntx*nty*(Cout/20)*BN;
}

extern "C" void kernel_launch(void* const* d_in, const int* in_sizes, int n_in,
                              void* d_out, int out_size, void* d_ws, size_t ws_size,
                              hipStream_t stream) {
    const float* x     = (const float*)d_in[0];
    const float* wr    = (const float*)d_in[1];
    const float* br    = (const float*)d_in[2];
    const float* wl    = (const float*)d_in[3];
    const float* bl    = (const float*)d_in[4];
    const float* w0a   = (const float*)d_in[5];
    const float* b0a   = (const float*)d_in[6];
    const float* w0b   = (const float*)d_in[7];
    const float* b0b   = (const float*)d_in[8];
    const float* wcb   = (const float*)d_in[9];
    const float* bcb   = (const float*)d_in[10];
    const float* wlast = (const float*)d_in[11];
    const float* blast = (const float*)d_in[12];

    float* ws      = (float*)d_ws;
    double* partial = (double*)d_ws;             // 32*GCHUNKS doubles = 4096 floats
    float* g       = ws + 4096;                  // 16 floats
    size_t off = 4112;
    float* flow = ws + off; off += (size_t)BN*4*HWF;
    float* mask = ws + off; off += (size_t)BN*1*HWF;
    float* wb0  = ws + off; off += (size_t)BN*3*HWF;
    float* wb1  = ws + off; off += (size_t)BN*3*HWF;
    float* tin  = ws + off; off += (size_t)BN*17*HWF;
    float* t0   = ws + off; off += (size_t)BN*40*(HF/2)*(WF/2);
    float* t1   = ws + off; off += (size_t)BN*80*(HF/4)*(WF/4);
    float* ra   = ws + off; off += (size_t)BN*80*(HF/4)*(WF/4);
    float* rb   = ws + off; off += (size_t)BN*80*(HF/4)*(WF/4);
    float* tmpb = ws + off; off += (size_t)BN*5*(HF/2)*(WF/2);
    float* wTc  = ws + off; off += (size_t)36*80*80*9;   // wcb transposed
    float* wTa  = ws + off; off += (size_t)9*17*40*9;    // w0a transposed
    float* wTb  = ws + off; off += (size_t)9*40*80*9;    // w0b transposed

    gate_conv_kernel<<<32*GCHUNKS, 256, 0, stream>>>(x, wr, br, partial);
    gate_fc_kernel<<<1, 64, 0, stream>>>(partial, wl, bl, g);
    {
        int n = 36*80*80*9;
        wtrans_kernel<<<(n+255)/256, 256, 0, stream>>>(wcb, wTc, 36, 80, 80);
        n = 9*40*17*9;
        wtrans_kernel<<<(n+255)/256, 256, 0, stream>>>(w0a, wTa, 9, 40, 17);
        n = 9*80*40*9;
        wtrans_kernel<<<(n+255)/256, 256, 0, stream>>>(w0b, wTb, 9, 80, 40);
    }
    {
        int n = BN*4*HWF;
        init_kernel<<<(n+255)/256, 256, 0, stream>>>(x, flow, mask, wb0, wb1);
    }
    const int SC[9] = {4,4,4,2,2,2,1,1,1};
    for (int i = 0; i < 9; ++i) {
        int s = SC[i];
        int sh = HF/s, sw = WF/s;
        int h = sh/2, w = sw/2;
        int h2 = h/2, w2 = w/2;
        {
            int n = BN*17*sh*sw;
            prepare_kernel<<<(n+255)/256,256,0,stream>>>(x, wb0, wb1, mask, flow, g, i, tin, s, sh, sw);
        }
        conv_lds_kernel<2><<<conv_grid(h, w, 40), 256, 0, stream>>>(
            tin, wTa + (size_t)i*17*9*40, b0a + i*40, nullptr, g, i, t0,
            17, 40, sh, sw, h, w);
        conv_lds_kernel<2><<<conv_grid(h2, w2, 80), 256, 0, stream>>>(
            t0, wTb + (size_t)i*40*9*80, b0b + i*80, nullptr, g, i, t1,
            40, 80, h, w, h2, w2);
        const float* cin = t1;
        float* cout = ra;
        for (int j = 0; j < 4; ++j) {
            const float* res = (j == 3) ? t1 : nullptr;
            conv_lds_kernel<1><<<conv_grid(h2, w2, 80), 256, 0, stream>>>(
                cin, wTc + ((size_t)i*4 + j)*80*9*80, bcb + ((size_t)i*4 + j)*80,
                res, g, i, cout, 80, 80, h2, w2, h2, w2);
            cin = cout;
            cout = (cout == ra) ? rb : ra;
        }
        {
            int n = BN*5*h*w;
            deconv_kernel<<<(n+255)/256,256,0,stream>>>(cin, wlast + (size_t)i*5*80*16, blast + i*5,
                g, i, tmpb, h2, w2);
        }
        {
            int n = BN*5*HWF;
            upsample_accum_kernel<<<(n+255)/256,256,0,stream>>>(tmpb, g, i, flow, mask, h, w, 2*s, (float)(2*s));
        }
        {
            int n = BN*6*HWF;
            warp_kernel<<<(n+255)/256,256,0,stream>>>(x, flow, g, i, wb0, wb1);
        }
    }
    {
        int n = BN*3*HWF;
        final_kernel<<<(n+255)/256,256,0,stream>>>(wb0, wb1, mask, (float*)d_out);
    }
}

// Round 6
// 2240.644 us; speedup vs baseline: 3.6459x; 1.4662x over previous
//
#include <hip/hip_runtime.h>
#include <hip/hip_bf16.h>
#include <cmath>

#define BN 4
#define HF 256
#define WF 448
#define HWF (HF*WF)   // 114688
#define GBLK 448      // HWF/256

typedef __attribute__((ext_vector_type(8))) short short8v;
typedef __attribute__((ext_vector_type(4))) float float4v;

__device__ __forceinline__ float clampf(float v, float lo, float hi) {
    return fminf(fmaxf(v, lo), hi);
}
__device__ __forceinline__ float bf2f(ushort u) {
    unsigned v = ((unsigned)u) << 16;
    return __builtin_bit_cast(float, v);
}
__device__ __forceinline__ ushort f2bf(float f) {
    unsigned u = __builtin_bit_cast(unsigned, f);
    unsigned r = u + 0x7FFFu + ((u >> 16) & 1u);   // RNE
    return (ushort)(r >> 16);
}

// ---- gate conv: 1 pixel/thread, all 32 channels; per-block partial sums ----
__global__ void gate_conv_kernel(const float* __restrict__ x,
                                 const float* __restrict__ wr,
                                 const float* __restrict__ br,
                                 double* __restrict__ partial) {
    __shared__ float wsh[32*54];
    __shared__ float bsh[32];
    int tid = threadIdx.x;
    for (int i = tid; i < 32*54; i += 256) wsh[i] = wr[i];
    if (tid < 32) bsh[tid] = br[tid];
    __syncthreads();
    int p = blockIdx.x*256 + tid;
    int y = p / WF, xx = p % WF;
    float acc[32];
    #pragma unroll
    for (int co = 0; co < 32; ++co) acc[co] = bsh[co];
    for (int ci = 0; ci < 6; ++ci) {
        const float* ip = x + (size_t)ci*HWF;
        float v[9];
        #pragma unroll
        for (int ky = 0; ky < 3; ++ky) {
            int iy = y + ky - 1;
            #pragma unroll
            for (int kx = 0; kx < 3; ++kx) {
                int ix = xx + kx - 1;
                v[ky*3+kx] = ((unsigned)iy < HF && (unsigned)ix < WF) ? ip[iy*WF+ix] : 0.0f;
            }
        }
        #pragma unroll
        for (int co = 0; co < 32; ++co) {
            const float* wp = &wsh[co*54 + ci*9];
            #pragma unroll
            for (int t = 0; t < 9; ++t) acc[co] = fmaf(v[t], wp[t], acc[co]);
        }
    }
    __shared__ float red[4][32];
    int lane = tid & 63, wave = tid >> 6;
    #pragma unroll
    for (int co = 0; co < 32; ++co) {
        float s = fmaxf(acc[co], 0.0f);
        for (int off = 32; off > 0; off >>= 1) s += __shfl_down(s, off);
        if (lane == 0) red[wave][co] = s;
    }
    __syncthreads();
    if (tid < 32) {
        double s = (double)red[0][tid] + (double)red[1][tid]
                 + (double)red[2][tid] + (double)red[3][tid];
        partial[tid*GBLK + blockIdx.x] = s;
    }
}

// ---- gate FC ----
__global__ void gate_fc_kernel(const double* __restrict__ partial,
                               const float* __restrict__ wl,
                               const float* __restrict__ bl,
                               float* __restrict__ g) {
    __shared__ double rm[32];
    __shared__ double v[9];
    int i = threadIdx.x;
    if (i < 32) {
        double s = 0.0;
        for (int k = 0; k < GBLK; ++k) s += partial[i*GBLK + k];
        rm[i] = s / (double)HWF;
    }
    __syncthreads();
    if (i < 9) {
        double t = (double)bl[i];
        for (int c = 0; c < 32; ++c) t += rm[c] * (double)wl[i*32+c];
        v[i] = 1.0 / (1.0 + exp(-t));
    }
    __syncthreads();
    if (i == 0) {
        double s = 0.0;
        for (int k = 0; k < 9; ++k) s += v[k];
        for (int k = 0; k < 9; ++k) {
            double vn = v[k] / (s + 1e-6) * 4.5;
            vn = vn < 0.0 ? 0.0 : (vn > 1.0 ? 1.0 : vn);
            g[k] = (float)rint(vn);
        }
    }
}

// ---- weight prep: w [nconv][Cout][Cin][9] f32 -> [nconv][2][9][CoP][Kpad] bf16 hi/lo ----
__global__ void wprep_kernel(const float* __restrict__ w, ushort* __restrict__ o,
                             int nconv, int Cout, int Cin, int CoP, int Kpad) {
    int idx = blockIdx.x*blockDim.x + threadIdx.x;
    int total = nconv*2*9*CoP*Kpad;
    if (idx >= total) return;
    int k   = idx % Kpad;
    int co  = (idx / Kpad) % CoP;
    int tap = (idx / (Kpad*CoP)) % 9;
    int pl  = (idx / (Kpad*CoP*9)) % 2;
    int cv  = idx / (Kpad*CoP*9*2);
    float v = 0.0f;
    if (co < Cout && k < Cin)
        v = w[(((size_t)cv*Cout + co)*Cin + k)*9 + tap];
    ushort hi = f2bf(v);
    o[idx] = (pl == 0) ? hi : f2bf(v - bf2f(hi));
}

// ---- init ----
__global__ void init_kernel(const float* __restrict__ x,
                            float* __restrict__ flow, float* __restrict__ mask,
                            float* __restrict__ w0, float* __restrict__ w1) {
    int idx = blockIdx.x * blockDim.x + threadIdx.x;
    if (idx < BN*4*HWF) flow[idx] = 0.0f;
    if (idx < BN*HWF)   mask[idx] = 0.0f;
    if (idx < BN*3*HWF) {
        int b = idx / (3*HWF), r = idx % (3*HWF);
        w0[idx] = x[(size_t)b*6*HWF + r];
        w1[idx] = x[(size_t)b*6*HWF + 3*HWF + r];
    }
}

// ---- prepare ----
__global__ void prepare_kernel(const float* __restrict__ x,
                               const float* __restrict__ w0buf, const float* __restrict__ w1buf,
                               const float* __restrict__ mask, const float* __restrict__ flow,
                               const float* __restrict__ g, int gi,
                               float* __restrict__ t, int s, int sh, int sw) {
    if (g[gi] == 0.0f) return;
    int idx = blockIdx.x * blockDim.x + threadIdx.x;
    int total = BN*17*sh*sw;
    if (idx >= total) return;
    int ox = idx % sw;
    int oy = (idx / sw) % sh;
    int c  = (idx / (sw*sh)) % 17;
    int b  = idx / (sw*sh*17);
    const float* src; float mult = 1.0f;
    if (c < 6)        src = x + ((size_t)b*6 + c)*HWF;
    else if (c < 9)   src = w0buf + ((size_t)b*3 + (c-6))*HWF;
    else if (c < 12)  src = w1buf + ((size_t)b*3 + (c-9))*HWF;
    else if (c == 12) src = mask + (size_t)b*HWF;
    else { src = flow + ((size_t)b*4 + (c-13))*HWF; mult = 1.0f / (float)s; }
    float val;
    if (s == 1) {
        val = src[oy*WF + ox];
    } else {
        int nt = 2*s;
        float posy = (oy + 0.5f)*(float)s - 0.5f;
        float posx = (ox + 0.5f)*(float)s - 0.5f;
        int jy0 = s*oy - s/2;
        int jx0 = s*ox - s/2;
        float wy[8], wx[8], sy = 0.f, sx = 0.f;
        for (int k = 0; k < nt; ++k) {
            int j = jy0 + k;
            float ww = 1.0f - fabsf((float)j - posy)/(float)s;
            if (j < 0 || j >= HF) ww = 0.f;
            wy[k] = ww; sy += ww;
        }
        for (int k = 0; k < nt; ++k) {
            int j = jx0 + k;
            float ww = 1.0f - fabsf((float)j - posx)/(float)s;
            if (j < 0 || j >= WF) ww = 0.f;
            wx[k] = ww; sx += ww;
        }
        float acc = 0.f;
        for (int a = 0; a < nt; ++a) {
            if (wy[a] == 0.f) continue;
            const float* rp = src + (jy0 + a)*WF;
            float rowacc = 0.f;
            for (int bb = 0; bb < nt; ++bb) {
                if (wx[bb] == 0.f) continue;
                rowacc += wx[bb] * rp[jx0 + bb];
            }
            acc += wy[a] * rowacc;
        }
        val = acc / (sy * sx);
    }
    t[idx] = val * mult;
}

// ---- split-bf16 MFMA implicit-GEMM 3x3 conv (3-term: WhiBhi + WhiBlo + WloBhi) ----
// fp32 in/out activations. S=1: pad 1; S=2: pad (0,1). relu(conv+bias) [+resid].
template<int S, int TWT, int THT, int CIN, int COUT>
__global__ __launch_bounds__(256, 2)
void conv_mfma_kernel(const float* __restrict__ in,
                      const ushort* __restrict__ wt,   // [2][9][COP][KPAD]
                      const float* __restrict__ bias,
                      const float* __restrict__ resid,
                      const float* __restrict__ g, int gi,
                      float* __restrict__ out,
                      int Hin, int Win, int Hout, int Wout) {
    if (g[gi] == 0.0f) return;
    constexpr int KPAD = ((CIN + 31)/32)*32;
    constexpr int KC   = KPAD/32;
    constexpr int COP  = (COUT == 40) ? 48 : 80;
    constexpr int MS   = COP/16;
    constexpr int PADO = (S == 1) ? 1 : 0;
    constexpr int IH   = THT*S + ((S == 1) ? 2 : 1);
    constexpr int IW   = TWT*S + ((S == 1) ? 2 : 1);
    constexpr int NS   = TWT*THT/16;
    constexpr int NPW  = NS/4;
    constexpr int P    = 40;       // chunk pitch (32 data + 8 pad) -> skewed banks
    constexpr int NPIX = IH*IW;

    __shared__ __align__(16) ushort sHi[NPIX*P];
    __shared__ __align__(16) ushort sLo[NPIX*P];

    int ntx = (Wout + TWT - 1)/TWT;
    int nty = Hout / THT;
    int bx  = blockIdx.x % ntx;
    int tmp = blockIdx.x / ntx;
    int by  = tmp % nty;
    int b   = tmp / nty;
    int x0 = bx*TWT, y0 = by*THT;

    int tid  = threadIdx.x;
    int lane = tid & 63;
    int wave = tid >> 6;
    int l15  = lane & 15;
    int l4   = lane >> 4;

    float4v acc[NPW][MS];
    #pragma unroll
    for (int n = 0; n < NPW; ++n)
        #pragma unroll
        for (int m = 0; m < MS; ++m)
            acc[n][m] = (float4v){0.f,0.f,0.f,0.f};

    const float* inb = in + (size_t)b*CIN*Hin*Win;

    for (int kc = 0; kc < KC; ++kc) {
        __syncthreads();
        // stage 32 channels, hi/lo split (rx fastest -> coalesced global)
        for (int idx = tid; idx < 32*NPIX; idx += 256) {
            int pix = idx % NPIX;
            int c   = idx / NPIX;
            int rx = pix % IW, ry = pix / IW;
            int ci = kc*32 + c;
            int gx = x0*S + rx - PADO;
            int gy = y0*S + ry - PADO;
            float v = 0.0f;
            if (ci < CIN && (unsigned)gx < (unsigned)Win && (unsigned)gy < (unsigned)Hin)
                v = inb[((size_t)ci*Hin + gy)*Win + gx];
            ushort hi = f2bf(v);
            sHi[pix*P + c] = hi;
            sLo[pix*P + c] = f2bf(v - bf2f(hi));
        }
        __syncthreads();
        #pragma unroll
        for (int tap = 0; tap < 9; ++tap) {
            int dy = tap/3, dx = tap%3;
            short8v bhi[NPW], blo[NPW];
            #pragma unroll
            for (int n = 0; n < NPW; ++n) {
                int pp = (wave*NPW + n)*16 + l15;
                int ty = pp / TWT, tx = pp % TWT;
                int offs = ((ty*S + dy)*IW + (tx*S + dx))*P + l4*8;
                bhi[n] = *(const short8v*)&sHi[offs];
                blo[n] = *(const short8v*)&sLo[offs];
            }
            #pragma unroll
            for (int m = 0; m < MS; ++m) {
                const ushort* wp = wt + ((size_t)(tap*COP + m*16 + l15))*KPAD + kc*32 + l4*8;
                short8v ahi = *(const short8v*)wp;
                short8v alo = *(const short8v*)(wp + (size_t)9*COP*KPAD);
                #pragma unroll
                for (int n = 0; n < NPW; ++n) {
                    acc[n][m] = __builtin_amdgcn_mfma_f32_16x16x32_bf16(ahi, bhi[n], acc[n][m], 0, 0, 0);
                    acc[n][m] = __builtin_amdgcn_mfma_f32_16x16x32_bf16(ahi, blo[n], acc[n][m], 0, 0, 0);
                    acc[n][m] = __builtin_amdgcn_mfma_f32_16x16x32_bf16(alo, bhi[n], acc[n][m], 0, 0, 0);
                }
            }
        }
    }

    size_t chw = (size_t)Hout*Wout;
    #pragma unroll
    for (int n = 0; n < NPW; ++n) {
        int pp = (wave*NPW + n)*16 + l15;
        int ty = pp / TWT, tx = pp % TWT;
        int oy = y0 + ty, ox = x0 + tx;
        if (ox < Wout) {
            #pragma unroll
            for (int m = 0; m < MS; ++m) {
                #pragma unroll
                for (int r = 0; r < 4; ++r) {
                    int co = m*16 + l4*4 + r;
                    if (co < COUT) {
                        float v = fmaxf(acc[n][m][r] + bias[co], 0.0f);
                        size_t o = ((size_t)b*COUT + co)*chw + (size_t)oy*Wout + ox;
                        if (resid) v += resid[o];
                        out[o] = v;
                    }
                }
            }
        }
    }
}

// ---- transposed conv 4x4 s2 (fp32) ----
__global__ void deconv_kernel(const float* __restrict__ t,
                              const float* __restrict__ wl,
                              const float* __restrict__ bl,
                              const float* __restrict__ g, int gi,
                              float* __restrict__ out,
                              int h2, int w2) {
    if (g[gi] == 0.0f) return;
    int ho = 2*h2, wo = 2*w2;
    int idx = blockIdx.x * blockDim.x + threadIdx.x;
    int total = BN*5*ho*wo;
    if (idx >= total) return;
    int xx = idx % wo;
    int y  = (idx / wo) % ho;
    int o  = (idx / (wo*ho)) % 5;
    int b  = idx / (wo*ho*5);
    float acc = bl[o];
    int p = y & 1, q = xx & 1;
    const float* tb = t + (size_t)b*80*h2*w2;
    for (int dy = 0; dy < 2; ++dy) {
        int ky = p + 2*dy;
        int iy = (y + ky - 2) >> 1;
        if ((unsigned)iy >= (unsigned)h2) continue;
        for (int dx = 0; dx < 2; ++dx) {
            int kx = q + 2*dx;
            int ix = (xx + kx - 2) >> 1;
            if ((unsigned)ix >= (unsigned)w2) continue;
            const float* tp = tb + iy*w2 + ix;
            const float* wp = wl + (size_t)o*80*16 + ky*4 + kx;
            for (int i = 0; i < 80; ++i)
                acc += tp[(size_t)i*h2*w2] * wp[i*16];
        }
    }
    out[idx] = acc;
}

// ---- bilinear upsample + gated accumulate ----
__global__ void upsample_accum_kernel(const float* __restrict__ tmp,
                                      const float* __restrict__ g, int gi,
                                      float* __restrict__ flow, float* __restrict__ mask,
                                      int h, int w, int f, float fdscale) {
    float gg = g[gi];
    if (gg == 0.0f) return;
    int idx = blockIdx.x * blockDim.x + threadIdx.x;
    int total = BN*5*HWF;
    if (idx >= total) return;
    int xx = idx % WF;
    int y  = (idx / WF) % HF;
    int c  = (idx / HWF) % 5;
    int b  = idx / (HWF*5);
    float posy = (y + 0.5f)/(float)f - 0.5f;
    float posx = (xx + 0.5f)/(float)f - 0.5f;
    float y0f = floorf(posy), x0f = floorf(posx);
    int jy0 = (int)y0f, jx0 = (int)x0f;
    float fy = posy - y0f, fx = posx - x0f;
    int jy1 = min(jy0 + 1, h-1), jx1 = min(jx0 + 1, w-1);
    jy0 = max(jy0, 0); jx0 = max(jx0, 0);
    const float* tp = tmp + ((size_t)(b*5 + c))*h*w;
    float v00 = tp[jy0*w + jx0], v01 = tp[jy0*w + jx1];
    float v10 = tp[jy1*w + jx0], v11 = tp[jy1*w + jx1];
    float val = v00*(1-fx)*(1-fy) + v01*fx*(1-fy) + v10*(1-fx)*fy + v11*fx*fy;
    int p2 = y*WF + xx;
    if (c < 4) flow[((size_t)b*4 + c)*HWF + p2] += val * fdscale * gg;
    else       mask[(size_t)b*HWF + p2] += val * gg;
}

// ---- warp ----
__global__ void warp_kernel(const float* __restrict__ x,
                            const float* __restrict__ flow,
                            const float* __restrict__ g, int gi,
                            float* __restrict__ w0, float* __restrict__ w1) {
    if (g[gi] == 0.0f) return;
    int idx = blockIdx.x*blockDim.x + threadIdx.x;
    int total = BN*6*HWF;
    if (idx >= total) return;
    int p  = idx % HWF;
    int c  = (idx / HWF) % 6;
    int b  = idx / (HWF*6);
    int xx = p % WF, y = p / WF;
    int which = (c >= 3) ? 1 : 0;
    const float* fl = flow + ((size_t)b*4 + which*2)*HWF;
    float sx = clampf((float)xx + fl[p], 0.f, (float)(WF-1));
    float sy = clampf((float)y  + fl[HWF + p], 0.f, (float)(HF-1));
    float x0f = floorf(sx), y0f = floorf(sy);
    int x0 = (int)x0f, y0 = (int)y0f;
    int x1 = min(x0 + 1, WF - 1), y1 = min(y0 + 1, HF - 1);
    float wx = sx - x0f, wy = sy - y0f;
    const float* im = x + ((size_t)b*6 + c)*HWF;
    float v00 = im[y0*WF + x0], v01 = im[y0*WF + x1];
    float v10 = im[y1*WF + x0], v11 = im[y1*WF + x1];
    float val = v00*(1-wx)*(1-wy) + v01*wx*(1-wy) + v10*(1-wx)*wy + v11*wx*wy;
    float* dst = which ? w1 : w0;
    dst[((size_t)b*3 + (c - which*3))*HWF + p] = val;
}

// ---- final blend ----
__global__ void final_kernel(const float* __restrict__ w0, const float* __restrict__ w1,
                             const float* __restrict__ mask, float* __restrict__ outp) {
    int idx = blockIdx.x*blockDim.x + threadIdx.x;
    if (idx >= BN*3*HWF) return;
    int p = idx % HWF;
    int b = idx / (3*HWF);
    float m = 1.0f / (1.0f + expf(-mask[(size_t)b*HWF + p]));
    float val = w0[idx]*m + w1[idx]*(1.0f - m);
    outp[idx] = clampf(val, 0.0f, 1.0f);
}

extern "C" void kernel_launch(void* const* d_in, const int* in_sizes, int n_in,
                              void* d_out, int out_size, void* d_ws, size_t ws_size,
                              hipStream_t stream) {
    const float* x     = (const float*)d_in[0];
    const float* wr    = (const float*)d_in[1];
    const float* br    = (const float*)d_in[2];
    const float* wl    = (const float*)d_in[3];
    const float* bl    = (const float*)d_in[4];
    const float* w0a   = (const float*)d_in[5];
    const float* b0a   = (const float*)d_in[6];
    const float* w0b   = (const float*)d_in[7];
    const float* b0b   = (const float*)d_in[8];
    const float* wcb   = (const float*)d_in[9];
    const float* bcb   = (const float*)d_in[10];
    const float* wlast = (const float*)d_in[11];
    const float* blast = (const float*)d_in[12];

    float* ws       = (float*)d_ws;
    double* partial = (double*)d_ws;             // 32*GBLK doubles = 28672 float slots
    float* g        = ws + 28672;                // 16 floats
    size_t off = 28688;
    float* flow = ws + off; off += (size_t)BN*4*HWF;            // 1,835,008
    float* mask = ws + off; off += (size_t)BN*1*HWF;            //   458,752
    float* wb0  = ws + off; off += (size_t)BN*3*HWF;            // 1,376,256
    float* wb1  = ws + off; off += (size_t)BN*3*HWF;            // 1,376,256
    float* tin  = ws + off; off += (size_t)BN*17*HWF;           // 7,798,784
    float* t0   = ws + off; off += (size_t)BN*40*(HF/2)*(WF/2); // 4,587,520
    float* tmpb = ws + off; off += (size_t)BN*5*(HF/2)*(WF/2);  //   573,440
    ushort* wTa2 = (ushort*)(ws + off); off += (size_t)9*2*9*48*32/2;   // 124,416
    ushort* wTb2 = (ushort*)(ws + off); off += (size_t)9*2*9*80*64/2;   // 414,720
    ushort* wTc2 = (ushort*)(ws + off); off += (size_t)36*2*9*80*96/2;  // 2,488,320
    // aliased buffers (lifetime-disjoint):
    float* ra = t0;              // ra live only after t0 is dead (post convB)
    float* rb = tin;             // rb live only after tin is dead (post convA)
    float* t1 = tin + 2400000;   // t1 live only after tin is dead

    gate_conv_kernel<<<GBLK, 256, 0, stream>>>(x, wr, br, partial);
    gate_fc_kernel<<<1, 64, 0, stream>>>(partial, wl, bl, g);
    {
        int n = 9*2*9*48*32;
        wprep_kernel<<<(n+255)/256, 256, 0, stream>>>(w0a, wTa2, 9, 40, 17, 48, 32);
        n = 9*2*9*80*64;
        wprep_kernel<<<(n+255)/256, 256, 0, stream>>>(w0b, wTb2, 9, 80, 40, 80, 64);
        n = 36*2*9*80*96;
        wprep_kernel<<<(n+255)/256, 256, 0, stream>>>(wcb, wTc2, 36, 80, 80, 80, 96);
    }
    {
        int n = BN*4*HWF;
        init_kernel<<<(n+255)/256, 256, 0, stream>>>(x, flow, mask, wb0, wb1);
    }
    const int SC[9] = {4,4,4,2,2,2,1,1,1};
    for (int i = 0; i < 9; ++i) {
        int s = SC[i];
        int sh = HF/s, sw = WF/s;
        int h = sh/2, w = sw/2;
        int h2 = h/2, w2 = w/2;
        {
            int n = BN*17*sh*sw;
            prepare_kernel<<<(n+255)/256,256,0,stream>>>(x, wb0, wb1, mask, flow, g, i, tin, s, sh, sw);
        }
        {   // 17->40 s2
            int ntx = (w + 7)/8, nty = h/8;
            conv_mfma_kernel<2,8,8,17,40><<<ntx*nty*BN, 256, 0, stream>>>(
                tin, wTa2 + (size_t)i*2*9*48*32, b0a + i*40, nullptr, g, i, t0, sh, sw, h, w);
        }
        {   // 40->80 s2
            int ntx = (w2 + 7)/8, nty = h2/8;
            conv_mfma_kernel<2,8,8,40,80><<<ntx*nty*BN, 256, 0, stream>>>(
                t0, wTb2 + (size_t)i*2*9*80*64, b0b + i*80, nullptr, g, i, t1, h, w, h2, w2);
        }
        {   // 4x 80->80 s1: t1 -> ra -> rb -> ra -> rb(+resid t1)
            int ntx = (w2 + 15)/16, nty = h2/8;
            int nblk = ntx*nty*BN;
            const float* cin = t1;
            float* cout = ra;
            for (int j = 0; j < 4; ++j) {
                const float* res = (j == 3) ? t1 : nullptr;
                conv_mfma_kernel<1,16,8,80,80><<<nblk, 256, 0, stream>>>(
                    cin, wTc2 + ((size_t)i*4 + j)*2*9*80*96, bcb + ((size_t)i*4 + j)*80,
                    res, g, i, cout, h2, w2, h2, w2);
                cin = cout;
                cout = (cout == ra) ? rb : ra;
            }
        }
        {
            int n = BN*5*h*w;
            deconv_kernel<<<(n+255)/256,256,0,stream>>>(rb, wlast + (size_t)i*5*80*16, blast + i*5,
                g, i, tmpb, h2, w2);
        }
        {
            int n = BN*5*HWF;
            upsample_accum_kernel<<<(n+255)/256,256,0,stream>>>(tmpb, g, i, flow, mask, h, w, 2*s, (float)(2*s));
        }
        {
            int n = BN*6*HWF;
            warp_kernel<<<(n+255)/256,256,0,stream>>>(x, flow, g, i, wb0, wb1);
        }
    }
    {
        int n = BN*3*HWF;
        final_kernel<<<(n+255)/256,256,0,stream>>>(wb0, wb1, mask, (float*)d_out);
    }
}

// Round 7
// 2126.052 us; speedup vs baseline: 3.8425x; 1.0539x over previous
//
#include <hip/hip_runtime.h>
#include <hip/hip_bf16.h>
#include <cmath>

#define BN 4
#define HF 256
#define WF 448
#define HWF (HF*WF)   // 114688
#define GBLK 448      // HWF/256

typedef __attribute__((ext_vector_type(8))) short short8v;
typedef __attribute__((ext_vector_type(4))) float float4v;

__device__ __forceinline__ float clampf(float v, float lo, float hi) {
    return fminf(fmaxf(v, lo), hi);
}
__device__ __forceinline__ float bf2f(ushort u) {
    unsigned v = ((unsigned)u) << 16;
    return __builtin_bit_cast(float, v);
}
__device__ __forceinline__ ushort f2bf(float f) {
    unsigned u = __builtin_bit_cast(unsigned, f);
    unsigned r = u + 0x7FFFu + ((u >> 16) & 1u);   // RNE
    return (ushort)(r >> 16);
}

// ---- gate conv: 1 pixel/thread, all 32 channels; per-block partial sums ----
__global__ void gate_conv_kernel(const float* __restrict__ x,
                                 const float* __restrict__ wr,
                                 const float* __restrict__ br,
                                 double* __restrict__ partial) {
    __shared__ float wsh[32*54];
    __shared__ float bsh[32];
    int tid = threadIdx.x;
    for (int i = tid; i < 32*54; i += 256) wsh[i] = wr[i];
    if (tid < 32) bsh[tid] = br[tid];
    __syncthreads();
    int p = blockIdx.x*256 + tid;
    int y = p / WF, xx = p % WF;
    float acc[32];
    #pragma unroll
    for (int co = 0; co < 32; ++co) acc[co] = bsh[co];
    for (int ci = 0; ci < 6; ++ci) {
        const float* ip = x + (size_t)ci*HWF;
        float v[9];
        #pragma unroll
        for (int ky = 0; ky < 3; ++ky) {
            int iy = y + ky - 1;
            #pragma unroll
            for (int kx = 0; kx < 3; ++kx) {
                int ix = xx + kx - 1;
                v[ky*3+kx] = ((unsigned)iy < HF && (unsigned)ix < WF) ? ip[iy*WF+ix] : 0.0f;
            }
        }
        #pragma unroll
        for (int co = 0; co < 32; ++co) {
            const float* wp = &wsh[co*54 + ci*9];
            #pragma unroll
            for (int t = 0; t < 9; ++t) acc[co] = fmaf(v[t], wp[t], acc[co]);
        }
    }
    __shared__ float red[4][32];
    int lane = tid & 63, wave = tid >> 6;
    #pragma unroll
    for (int co = 0; co < 32; ++co) {
        float s = fmaxf(acc[co], 0.0f);
        for (int off = 32; off > 0; off >>= 1) s += __shfl_down(s, off);
        if (lane == 0) red[wave][co] = s;
    }
    __syncthreads();
    if (tid < 32) {
        double s = (double)red[0][tid] + (double)red[1][tid]
                 + (double)red[2][tid] + (double)red[3][tid];
        partial[tid*GBLK + blockIdx.x] = s;
    }
}

// ---- gate FC ----
__global__ void gate_fc_kernel(const double* __restrict__ partial,
                               const float* __restrict__ wl,
                               const float* __restrict__ bl,
                               float* __restrict__ g) {
    __shared__ double rm[32];
    __shared__ double v[9];
    int i = threadIdx.x;
    if (i < 32) {
        double s = 0.0;
        for (int k = 0; k < GBLK; ++k) s += partial[i*GBLK + k];
        rm[i] = s / (double)HWF;
    }
    __syncthreads();
    if (i < 9) {
        double t = (double)bl[i];
        for (int c = 0; c < 32; ++c) t += rm[c] * (double)wl[i*32+c];
        v[i] = 1.0 / (1.0 + exp(-t));
    }
    __syncthreads();
    if (i == 0) {
        double s = 0.0;
        for (int k = 0; k < 9; ++k) s += v[k];
        for (int k = 0; k < 9; ++k) {
            double vn = v[k] / (s + 1e-6) * 4.5;
            vn = vn < 0.0 ? 0.0 : (vn > 1.0 ? 1.0 : vn);
            g[k] = (float)rint(vn);
        }
    }
}

// ---- weight prep: w [nconv][Cout][Cin][9] f32 -> [nconv][2][9][CoP][Kpad] bf16 hi/lo ----
// hi = truncation (top 16 bits), lo = RNE(v - hi)
__global__ void wprep_kernel(const float* __restrict__ w, ushort* __restrict__ o,
                             int nconv, int Cout, int Cin, int CoP, int Kpad) {
    int idx = blockIdx.x*blockDim.x + threadIdx.x;
    int total = nconv*2*9*CoP*Kpad;
    if (idx >= total) return;
    int k   = idx % Kpad;
    int co  = (idx / Kpad) % CoP;
    int tap = (idx / (Kpad*CoP)) % 9;
    int pl  = (idx / (Kpad*CoP*9)) % 2;
    int cv  = idx / (Kpad*CoP*9*2);
    float v = 0.0f;
    if (co < Cout && k < Cin)
        v = w[(((size_t)cv*Cout + co)*Cin + k)*9 + tap];
    unsigned u = __builtin_bit_cast(unsigned, v);
    ushort hi = (ushort)(u >> 16);
    o[idx] = (pl == 0) ? hi : f2bf(v - bf2f(hi));
}

// ---- init ----
__global__ void init_kernel(const float* __restrict__ x,
                            float* __restrict__ flow, float* __restrict__ mask,
                            float* __restrict__ w0, float* __restrict__ w1) {
    int idx = blockIdx.x * blockDim.x + threadIdx.x;
    if (idx < BN*4*HWF) flow[idx] = 0.0f;
    if (idx < BN*HWF)   mask[idx] = 0.0f;
    if (idx < BN*3*HWF) {
        int b = idx / (3*HWF), r = idx % (3*HWF);
        w0[idx] = x[(size_t)b*6*HWF + r];
        w1[idx] = x[(size_t)b*6*HWF + 3*HWF + r];
    }
}

// ---- prepare ----
__global__ void prepare_kernel(const float* __restrict__ x,
                               const float* __restrict__ w0buf, const float* __restrict__ w1buf,
                               const float* __restrict__ mask, const float* __restrict__ flow,
                               const float* __restrict__ g, int gi,
                               float* __restrict__ t, int s, int sh, int sw) {
    if (g[gi] == 0.0f) return;
    int idx = blockIdx.x * blockDim.x + threadIdx.x;
    int total = BN*17*sh*sw;
    if (idx >= total) return;
    int ox = idx % sw;
    int oy = (idx / sw) % sh;
    int c  = (idx / (sw*sh)) % 17;
    int b  = idx / (sw*sh*17);
    const float* src; float mult = 1.0f;
    if (c < 6)        src = x + ((size_t)b*6 + c)*HWF;
    else if (c < 9)   src = w0buf + ((size_t)b*3 + (c-6))*HWF;
    else if (c < 12)  src = w1buf + ((size_t)b*3 + (c-9))*HWF;
    else if (c == 12) src = mask + (size_t)b*HWF;
    else { src = flow + ((size_t)b*4 + (c-13))*HWF; mult = 1.0f / (float)s; }
    float val;
    if (s == 1) {
        val = src[oy*WF + ox];
    } else {
        int nt = 2*s;
        float posy = (oy + 0.5f)*(float)s - 0.5f;
        float posx = (ox + 0.5f)*(float)s - 0.5f;
        int jy0 = s*oy - s/2;
        int jx0 = s*ox - s/2;
        float wy[8], wx[8], sy = 0.f, sx = 0.f;
        for (int k = 0; k < nt; ++k) {
            int j = jy0 + k;
            float ww = 1.0f - fabsf((float)j - posy)/(float)s;
            if (j < 0 || j >= HF) ww = 0.f;
            wy[k] = ww; sy += ww;
        }
        for (int k = 0; k < nt; ++k) {
            int j = jx0 + k;
            float ww = 1.0f - fabsf((float)j - posx)/(float)s;
            if (j < 0 || j >= WF) ww = 0.f;
            wx[k] = ww; sx += ww;
        }
        float acc = 0.f;
        for (int a = 0; a < nt; ++a) {
            if (wy[a] == 0.f) continue;
            const float* rp = src + (jy0 + a)*WF;
            float rowacc = 0.f;
            for (int bb = 0; bb < nt; ++bb) {
                if (wx[bb] == 0.f) continue;
                rowacc += wx[bb] * rp[jx0 + bb];
            }
            acc += wy[a] * rowacc;
        }
        val = acc / (sy * sx);
    }
    t[idx] = val * mult;
}

// ---- split-bf16 MFMA implicit-GEMM 3x3 conv, 128-thread (2-wave) blocks ----
// tile = 16 x THT outputs; S=1 -> THT=4 (NPW=2), S=2 -> THT=2 (NPW=1)
template<int S, int THT, int CIN, int COUT>
__global__ __launch_bounds__(128, 2)
void conv_mfma_kernel(const float* __restrict__ in,
                      const ushort* __restrict__ wt,   // [2][9][COP][KPAD]
                      const float* __restrict__ bias,
                      const float* __restrict__ resid,
                      const float* __restrict__ g, int gi,
                      float* __restrict__ out,
                      int Hin, int Win, int Hout, int Wout) {
    if (g[gi] == 0.0f) return;
    constexpr int KPAD = ((CIN + 31)/32)*32;
    constexpr int KC   = KPAD/32;
    constexpr int COP  = (COUT == 40) ? 48 : 80;
    constexpr int MS   = COP/16;
    constexpr int PADO = (S == 1) ? 1 : 0;
    constexpr int IH   = THT*S + ((S == 1) ? 2 : 1);
    constexpr int IW   = 16*S  + ((S == 1) ? 2 : 1);
    constexpr int NPW  = THT/2;      // subtiles per wave
    constexpr int P    = 40;         // pitch: 32 data + 8 pad ushorts (80B, 16B-aligned)
    constexpr int NPIX = IH*IW;

    __shared__ __align__(16) ushort sHi[NPIX*P];
    __shared__ __align__(16) ushort sLo[NPIX*P];

    int ntx = (Wout + 15)/16;
    int nty = Hout / THT;
    int bx  = blockIdx.x % ntx;
    int tmp = blockIdx.x / ntx;
    int by  = tmp % nty;
    int b   = tmp / nty;
    int x0 = bx*16, y0 = by*THT;

    int tid  = threadIdx.x;
    int lane = tid & 63;
    int wave = tid >> 6;
    int l15  = lane & 15;
    int l4   = lane >> 4;

    float4v acc[NPW][MS];
    #pragma unroll
    for (int n = 0; n < NPW; ++n)
        #pragma unroll
        for (int m = 0; m < MS; ++m)
            acc[n][m] = (float4v){0.f,0.f,0.f,0.f};

    const float* inb = in + (size_t)b*CIN*Hin*Win;

    for (int kc = 0; kc < KC; ++kc) {
        __syncthreads();
        // stage 32 channels, hi(trunc)/lo(rne) split; pix fastest -> coalesced
        for (int idx = tid; idx < 32*NPIX; idx += 128) {
            int pix = idx % NPIX;
            int c   = idx / NPIX;
            int rx = pix % IW, ry = pix / IW;
            int ci = kc*32 + c;
            int gx = x0*S + rx - PADO;
            int gy = y0*S + ry - PADO;
            float v = 0.0f;
            if (ci < CIN && (unsigned)gx < (unsigned)Win && (unsigned)gy < (unsigned)Hin)
                v = inb[((size_t)ci*Hin + gy)*Win + gx];
            unsigned u = __builtin_bit_cast(unsigned, v);
            ushort hi = (ushort)(u >> 16);
            sHi[pix*P + c] = hi;
            sLo[pix*P + c] = f2bf(v - bf2f(hi));
        }
        __syncthreads();
        #pragma unroll
        for (int tap = 0; tap < 9; ++tap) {
            int dy = tap/3, dx = tap%3;
            short8v bhi[NPW], blo[NPW];
            #pragma unroll
            for (int n = 0; n < NPW; ++n) {
                int pp = (wave*NPW + n)*16 + l15;
                int ty = pp >> 4, tx = pp & 15;
                int offs = ((ty*S + dy)*IW + (tx*S + dx))*P + l4*8;
                bhi[n] = *(const short8v*)&sHi[offs];
                blo[n] = *(const short8v*)&sLo[offs];
            }
            #pragma unroll
            for (int m = 0; m < MS; ++m) {
                const ushort* wp = wt + ((size_t)(tap*COP + m*16 + l15))*KPAD + kc*32 + l4*8;
                short8v ahi = *(const short8v*)wp;
                short8v alo = *(const short8v*)(wp + (size_t)9*COP*KPAD);
                #pragma unroll
                for (int n = 0; n < NPW; ++n) {
                    acc[n][m] = __builtin_amdgcn_mfma_f32_16x16x32_bf16(ahi, bhi[n], acc[n][m], 0, 0, 0);
                    acc[n][m] = __builtin_amdgcn_mfma_f32_16x16x32_bf16(ahi, blo[n], acc[n][m], 0, 0, 0);
                    acc[n][m] = __builtin_amdgcn_mfma_f32_16x16x32_bf16(alo, bhi[n], acc[n][m], 0, 0, 0);
                }
            }
        }
    }

    size_t chw = (size_t)Hout*Wout;
    #pragma unroll
    for (int n = 0; n < NPW; ++n) {
        int pp = (wave*NPW + n)*16 + l15;
        int ty = pp >> 4, tx = pp & 15;
        int oy = y0 + ty, ox = x0 + tx;
        if (ox < Wout) {
            #pragma unroll
            for (int m = 0; m < MS; ++m) {
                #pragma unroll
                for (int r = 0; r < 4; ++r) {
                    int co = m*16 + l4*4 + r;
                    if (co < COUT) {
                        float v = fmaxf(acc[n][m][r] + bias[co], 0.0f);
                        size_t o = ((size_t)b*COUT + co)*chw + (size_t)oy*Wout + ox;
                        if (resid) v += resid[o];
                        out[o] = v;
                    }
                }
            }
        }
    }
}

// ---- transposed conv 4x4 s2 (fp32) ----
__global__ void deconv_kernel(const float* __restrict__ t,
                              const float* __restrict__ wl,
                              const float* __restrict__ bl,
                              const float* __restrict__ g, int gi,
                              float* __restrict__ out,
                              int h2, int w2) {
    if (g[gi] == 0.0f) return;
    int ho = 2*h2, wo = 2*w2;
    int idx = blockIdx.x * blockDim.x + threadIdx.x;
    int total = BN*5*ho*wo;
    if (idx >= total) return;
    int xx = idx % wo;
    int y  = (idx / wo) % ho;
    int o  = (idx / (wo*ho)) % 5;
    int b  = idx / (wo*ho*5);
    float acc = bl[o];
    int p = y & 1, q = xx & 1;
    const float* tb = t + (size_t)b*80*h2*w2;
    for (int dy = 0; dy < 2; ++dy) {
        int ky = p + 2*dy;
        int iy = (y + ky - 2) >> 1;
        if ((unsigned)iy >= (unsigned)h2) continue;
        for (int dx = 0; dx < 2; ++dx) {
            int kx = q + 2*dx;
            int ix = (xx + kx - 2) >> 1;
            if ((unsigned)ix >= (unsigned)w2) continue;
            const float* tp = tb + iy*w2 + ix;
            const float* wp = wl + (size_t)o*80*16 + ky*4 + kx;
            for (int i = 0; i < 80; ++i)
                acc += tp[(size_t)i*h2*w2] * wp[i*16];
        }
    }
    out[idx] = acc;
}

// ---- fused: bilinear upsample + gated flow/mask accumulate + backward warp ----
// one thread per (b, pixel); updates flow/mask, then warps img0/img1 with new flow
__global__ void upwarp_kernel(const float* __restrict__ tmp,
                              const float* __restrict__ x,
                              const float* __restrict__ g, int gi,
                              float* __restrict__ flow, float* __restrict__ mask,
                              float* __restrict__ w0, float* __restrict__ w1,
                              int h, int w, int f, float fdscale) {
    float gg = g[gi];
    if (gg == 0.0f) return;
    int idx = blockIdx.x * blockDim.x + threadIdx.x;
    if (idx >= BN*HWF) return;
    int p2 = idx % HWF;
    int b  = idx / HWF;
    int xx = p2 % WF, y = p2 / WF;

    // upsample coords (output pixel -> tmp grid)
    float posy = (y + 0.5f)/(float)f - 0.5f;
    float posx = (xx + 0.5f)/(float)f - 0.5f;
    float y0f = floorf(posy), x0f = floorf(posx);
    int jy0 = (int)y0f, jx0 = (int)x0f;
    float fy = posy - y0f, fx = posx - x0f;
    int jy1 = min(jy0 + 1, h-1), jx1 = min(jx0 + 1, w-1);
    jy0 = max(jy0, 0); jx0 = max(jx0, 0);
    float w00 = (1-fx)*(1-fy), w01 = fx*(1-fy), w10 = (1-fx)*fy, w11 = fx*fy;

    float fl[4];
    #pragma unroll
    for (int c = 0; c < 4; ++c) {
        const float* tp = tmp + ((size_t)(b*5 + c))*h*w;
        float val = tp[jy0*w+jx0]*w00 + tp[jy0*w+jx1]*w01 + tp[jy1*w+jx0]*w10 + tp[jy1*w+jx1]*w11;
        size_t fo = ((size_t)b*4 + c)*HWF + p2;
        float nf = flow[fo] + val * fdscale * gg;
        flow[fo] = nf;
        fl[c] = nf;
    }
    {
        const float* tp = tmp + ((size_t)(b*5 + 4))*h*w;
        float val = tp[jy0*w+jx0]*w00 + tp[jy0*w+jx1]*w01 + tp[jy1*w+jx0]*w10 + tp[jy1*w+jx1]*w11;
        mask[(size_t)b*HWF + p2] += val * gg;
    }

    // warp img0 with fl[0..1] -> w0, img1 with fl[2..3] -> w1
    #pragma unroll
    for (int which = 0; which < 2; ++which) {
        float sx = clampf((float)xx + fl[which*2+0], 0.f, (float)(WF-1));
        float sy = clampf((float)y  + fl[which*2+1], 0.f, (float)(HF-1));
        float sx0f = floorf(sx), sy0f = floorf(sy);
        int ix0 = (int)sx0f, iy0 = (int)sy0f;
        int ix1 = min(ix0 + 1, WF - 1), iy1 = min(iy0 + 1, HF - 1);
        float wx = sx - sx0f, wy = sy - sy0f;
        float a00 = (1-wx)*(1-wy), a01 = wx*(1-wy), a10 = (1-wx)*wy, a11 = wx*wy;
        float* dst = which ? w1 : w0;
        #pragma unroll
        for (int c = 0; c < 3; ++c) {
            const float* im = x + ((size_t)b*6 + which*3 + c)*HWF;
            float val = im[iy0*WF+ix0]*a00 + im[iy0*WF+ix1]*a01
                      + im[iy1*WF+ix0]*a10 + im[iy1*WF+ix1]*a11;
            dst[((size_t)b*3 + c)*HWF + p2] = val;
        }
    }
}

// ---- final blend ----
__global__ void final_kernel(const float* __restrict__ w0, const float* __restrict__ w1,
                             const float* __restrict__ mask, float* __restrict__ outp) {
    int idx = blockIdx.x*blockDim.x + threadIdx.x;
    if (idx >= BN*3*HWF) return;
    int p = idx % HWF;
    int b = idx / (3*HWF);
    float m = 1.0f / (1.0f + expf(-mask[(size_t)b*HWF + p]));
    float val = w0[idx]*m + w1[idx]*(1.0f - m);
    outp[idx] = clampf(val, 0.0f, 1.0f);
}

extern "C" void kernel_launch(void* const* d_in, const int* in_sizes, int n_in,
                              void* d_out, int out_size, void* d_ws, size_t ws_size,
                              hipStream_t stream) {
    const float* x     = (const float*)d_in[0];
    const float* wr    = (const float*)d_in[1];
    const float* br    = (const float*)d_in[2];
    const float* wl    = (const float*)d_in[3];
    const float* bl    = (const float*)d_in[4];
    const float* w0a   = (const float*)d_in[5];
    const float* b0a   = (const float*)d_in[6];
    const float* w0b   = (const float*)d_in[7];
    const float* b0b   = (const float*)d_in[8];
    const float* wcb   = (const float*)d_in[9];
    const float* bcb   = (const float*)d_in[10];
    const float* wlast = (const float*)d_in[11];
    const float* blast = (const float*)d_in[12];

    float* ws       = (float*)d_ws;
    double* partial = (double*)d_ws;             // 32*GBLK doubles = 28672 float slots
    float* g        = ws + 28672;                // 16 floats
    size_t off = 28688;
    float* flow = ws + off; off += (size_t)BN*4*HWF;
    float* mask = ws + off; off += (size_t)BN*1*HWF;
    float* wb0  = ws + off; off += (size_t)BN*3*HWF;
    float* wb1  = ws + off; off += (size_t)BN*3*HWF;
    float* tin  = ws + off; off += (size_t)BN*17*HWF;
    float* t0   = ws + off; off += (size_t)BN*40*(HF/2)*(WF/2);
    float* tmpb = ws + off; off += (size_t)BN*5*(HF/2)*(WF/2);
    ushort* wTa2 = (ushort*)(ws + off); off += (size_t)9*2*9*48*32/2;
    ushort* wTb2 = (ushort*)(ws + off); off += (size_t)9*2*9*80*64/2;
    ushort* wTc2 = (ushort*)(ws + off); off += (size_t)36*2*9*80*96/2;
    // aliased buffers (lifetime-disjoint):
    float* ra = t0;              // live only after t0 dead (post convB)
    float* rb = tin;             // live only after tin dead (post convA)
    float* t1 = tin + 2400000;   // live only after tin dead

    gate_conv_kernel<<<GBLK, 256, 0, stream>>>(x, wr, br, partial);
    gate_fc_kernel<<<1, 64, 0, stream>>>(partial, wl, bl, g);
    {
        int n = 9*2*9*48*32;
        wprep_kernel<<<(n+255)/256, 256, 0, stream>>>(w0a, wTa2, 9, 40, 17, 48, 32);
        n = 9*2*9*80*64;
        wprep_kernel<<<(n+255)/256, 256, 0, stream>>>(w0b, wTb2, 9, 80, 40, 80, 64);
        n = 36*2*9*80*96;
        wprep_kernel<<<(n+255)/256, 256, 0, stream>>>(wcb, wTc2, 36, 80, 80, 80, 96);
    }
    {
        int n = BN*4*HWF;
        init_kernel<<<(n+255)/256, 256, 0, stream>>>(x, flow, mask, wb0, wb1);
    }
    const int SC[9] = {4,4,4,2,2,2,1,1,1};
    for (int i = 0; i < 9; ++i) {
        int s = SC[i];
        int sh = HF/s, sw = WF/s;
        int h = sh/2, w = sw/2;
        int h2 = h/2, w2 = w/2;
        {
            int n = BN*17*sh*sw;
            prepare_kernel<<<(n+255)/256,256,0,stream>>>(x, wb0, wb1, mask, flow, g, i, tin, s, sh, sw);
        }
        {   // 17->40 s2, THT=2
            int ntx = (w + 15)/16, nty = h/2;
            conv_mfma_kernel<2,2,17,40><<<ntx*nty*BN, 128, 0, stream>>>(
                tin, wTa2 + (size_t)i*2*9*48*32, b0a + i*40, nullptr, g, i, t0, sh, sw, h, w);
        }
        {   // 40->80 s2, THT=2
            int ntx = (w2 + 15)/16, nty = h2/2;
            conv_mfma_kernel<2,2,40,80><<<ntx*nty*BN, 128, 0, stream>>>(
                t0, wTb2 + (size_t)i*2*9*80*64, b0b + i*80, nullptr, g, i, t1, h, w, h2, w2);
        }
        {   // 4x 80->80 s1, THT=4: t1 -> ra -> rb -> ra -> rb(+resid t1)
            int ntx = (w2 + 15)/16, nty = h2/4;
            int nblk = ntx*nty*BN;
            const float* cin = t1;
            float* cout = ra;
            for (int j = 0; j < 4; ++j) {
                const float* res = (j == 3) ? t1 : nullptr;
                conv_mfma_kernel<1,4,80,80><<<nblk, 128, 0, stream>>>(
                    cin, wTc2 + ((size_t)i*4 + j)*2*9*80*96, bcb + ((size_t)i*4 + j)*80,
                    res, g, i, cout, h2, w2, h2, w2);
                cin = cout;
                cout = (cout == ra) ? rb : ra;
            }
        }
        {
            int n = BN*5*h*w;
            deconv_kernel<<<(n+255)/256,256,0,stream>>>(rb, wlast + (size_t)i*5*80*16, blast + i*5,
                g, i, tmpb, h2, w2);
        }
        {
            int n = BN*HWF;
            upwarp_kernel<<<(n+255)/256,256,0,stream>>>(tmpb, x, g, i, flow, mask, wb0, wb1,
                h, w, 2*s, (float)(2*s));
        }
    }
    {
        int n = BN*3*HWF;
        final_kernel<<<(n+255)/256,256,0,stream>>>(wb0, wb1, mask, (float*)d_out);
    }
}

// Round 8
// 1723.759 us; speedup vs baseline: 4.7392x; 1.2334x over previous
//
#include <hip/hip_runtime.h>
#include <hip/hip_bf16.h>
#include <cmath>

#define BN 4
#define HF 256
#define WF 448
#define HWF (HF*WF)   // 114688
#define GBLK 448      // HWF/256

typedef __attribute__((ext_vector_type(8))) short short8v;
typedef __attribute__((ext_vector_type(4))) float float4v;

__device__ __forceinline__ float clampf(float v, float lo, float hi) {
    return fminf(fmaxf(v, lo), hi);
}
__device__ __forceinline__ float bf2f(ushort u) {
    unsigned v = ((unsigned)u) << 16;
    return __builtin_bit_cast(float, v);
}
__device__ __forceinline__ ushort f2bf(float f) {
    unsigned u = __builtin_bit_cast(unsigned, f);
    unsigned r = u + 0x7FFFu + ((u >> 16) & 1u);   // RNE
    return (ushort)(r >> 16);
}
__device__ __forceinline__ uint packhl(float v) {
    unsigned u = __builtin_bit_cast(unsigned, v);
    ushort hi = (ushort)(u >> 16);                 // trunc
    ushort lo = f2bf(v - bf2f(hi));                // exact remainder, RNE
    return ((uint)hi << 16) | lo;
}
__device__ __forceinline__ float unpackhl(uint u) {
    return bf2f((ushort)(u >> 16)) + bf2f((ushort)(u & 0xffffu));
}

// ---- gate conv: 1 pixel/thread, all 32 channels; per-block partial sums ----
__global__ void gate_conv_kernel(const float* __restrict__ x,
                                 const float* __restrict__ wr,
                                 const float* __restrict__ br,
                                 double* __restrict__ partial) {
    __shared__ float wsh[32*54];
    __shared__ float bsh[32];
    int tid = threadIdx.x;
    for (int i = tid; i < 32*54; i += 256) wsh[i] = wr[i];
    if (tid < 32) bsh[tid] = br[tid];
    __syncthreads();
    int p = blockIdx.x*256 + tid;
    int y = p / WF, xx = p % WF;
    float acc[32];
    #pragma unroll
    for (int co = 0; co < 32; ++co) acc[co] = bsh[co];
    for (int ci = 0; ci < 6; ++ci) {
        const float* ip = x + (size_t)ci*HWF;
        float v[9];
        #pragma unroll
        for (int ky = 0; ky < 3; ++ky) {
            int iy = y + ky - 1;
            #pragma unroll
            for (int kx = 0; kx < 3; ++kx) {
                int ix = xx + kx - 1;
                v[ky*3+kx] = ((unsigned)iy < HF && (unsigned)ix < WF) ? ip[iy*WF+ix] : 0.0f;
            }
        }
        #pragma unroll
        for (int co = 0; co < 32; ++co) {
            const float* wp = &wsh[co*54 + ci*9];
            #pragma unroll
            for (int t = 0; t < 9; ++t) acc[co] = fmaf(v[t], wp[t], acc[co]);
        }
    }
    __shared__ float red[4][32];
    int lane = tid & 63, wave = tid >> 6;
    #pragma unroll
    for (int co = 0; co < 32; ++co) {
        float s = fmaxf(acc[co], 0.0f);
        for (int off = 32; off > 0; off >>= 1) s += __shfl_down(s, off);
        if (lane == 0) red[wave][co] = s;
    }
    __syncthreads();
    if (tid < 32) {
        double s = (double)red[0][tid] + (double)red[1][tid]
                 + (double)red[2][tid] + (double)red[3][tid];
        partial[tid*GBLK + blockIdx.x] = s;
    }
}

// ---- gate FC ----
__global__ void gate_fc_kernel(const double* __restrict__ partial,
                               const float* __restrict__ wl,
                               const float* __restrict__ bl,
                               float* __restrict__ g) {
    __shared__ double rm[32];
    __shared__ double v[9];
    int i = threadIdx.x;
    if (i < 32) {
        double s = 0.0;
        for (int k = 0; k < GBLK; ++k) s += partial[i*GBLK + k];
        rm[i] = s / (double)HWF;
    }
    __syncthreads();
    if (i < 9) {
        double t = (double)bl[i];
        for (int c = 0; c < 32; ++c) t += rm[c] * (double)wl[i*32+c];
        v[i] = 1.0 / (1.0 + exp(-t));
    }
    __syncthreads();
    if (i == 0) {
        double s = 0.0;
        for (int k = 0; k < 9; ++k) s += v[k];
        for (int k = 0; k < 9; ++k) {
            double vn = v[k] / (s + 1e-6) * 4.5;
            vn = vn < 0.0 ? 0.0 : (vn > 1.0 ? 1.0 : vn);
            g[k] = (float)rint(vn);
        }
    }
}

// ---- weight prep: w [nconv][Cout][Cin][9] f32 -> [nconv][2][9][CoP][Kpad] bf16 hi/lo ----
__global__ void wprep_kernel(const float* __restrict__ w, ushort* __restrict__ o,
                             int nconv, int Cout, int Cin, int CoP, int Kpad) {
    int idx = blockIdx.x*blockDim.x + threadIdx.x;
    int total = nconv*2*9*CoP*Kpad;
    if (idx >= total) return;
    int k   = idx % Kpad;
    int co  = (idx / Kpad) % CoP;
    int tap = (idx / (Kpad*CoP)) % 9;
    int pl  = (idx / (Kpad*CoP*9)) % 2;
    int cv  = idx / (Kpad*CoP*9*2);
    float v = 0.0f;
    if (co < Cout && k < Cin)
        v = w[(((size_t)cv*Cout + co)*Cin + k)*9 + tap];
    unsigned u = __builtin_bit_cast(unsigned, v);
    ushort hi = (ushort)(u >> 16);
    o[idx] = (pl == 0) ? hi : f2bf(v - bf2f(hi));
}

// ---- init ----
__global__ void init_kernel(const float* __restrict__ x,
                            float* __restrict__ flow, float* __restrict__ mask,
                            float* __restrict__ w0, float* __restrict__ w1) {
    int idx = blockIdx.x * blockDim.x + threadIdx.x;
    if (idx < BN*4*HWF) flow[idx] = 0.0f;
    if (idx < BN*HWF)   mask[idx] = 0.0f;
    if (idx < BN*3*HWF) {
        int b = idx / (3*HWF), r = idx % (3*HWF);
        w0[idx] = x[(size_t)b*6*HWF + r];
        w1[idx] = x[(size_t)b*6*HWF + 3*HWF + r];
    }
}

// ---- prepare: packed-NHWC [b][sh+1][sw+1][17], halo row/col zeroed ----
__global__ void prepare_kernel(const float* __restrict__ x,
                               const float* __restrict__ w0buf, const float* __restrict__ w1buf,
                               const float* __restrict__ mask, const float* __restrict__ flow,
                               const float* __restrict__ g, int gi,
                               uint* __restrict__ t, int s, int sh, int sw) {
    if (g[gi] == 0.0f) return;
    int SW1 = sw+1, SH1 = sh+1;
    int idx = blockIdx.x * blockDim.x + threadIdx.x;
    int total = BN*SH1*SW1*17;
    if (idx >= total) return;
    int c  = idx % 17;
    int ox = (idx/17) % SW1;
    int oy = (idx/(17*SW1)) % SH1;
    int b  = idx/(17*SW1*SH1);
    if (ox == sw || oy == sh) { t[idx] = 0u; return; }
    const float* src; float mult = 1.0f;
    if (c < 6)        src = x + ((size_t)b*6 + c)*HWF;
    else if (c < 9)   src = w0buf + ((size_t)b*3 + (c-6))*HWF;
    else if (c < 12)  src = w1buf + ((size_t)b*3 + (c-9))*HWF;
    else if (c == 12) src = mask + (size_t)b*HWF;
    else { src = flow + ((size_t)b*4 + (c-13))*HWF; mult = 1.0f / (float)s; }
    float val;
    if (s == 1) {
        val = src[oy*WF + ox];
    } else {
        int nt = 2*s;
        float posy = (oy + 0.5f)*(float)s - 0.5f;
        float posx = (ox + 0.5f)*(float)s - 0.5f;
        int jy0 = s*oy - s/2;
        int jx0 = s*ox - s/2;
        float wy[8], wx[8], sy = 0.f, sx = 0.f;
        for (int k = 0; k < nt; ++k) {
            int j = jy0 + k;
            float ww = 1.0f - fabsf((float)j - posy)/(float)s;
            if (j < 0 || j >= HF) ww = 0.f;
            wy[k] = ww; sy += ww;
        }
        for (int k = 0; k < nt; ++k) {
            int j = jx0 + k;
            float ww = 1.0f - fabsf((float)j - posx)/(float)s;
            if (j < 0 || j >= WF) ww = 0.f;
            wx[k] = ww; sx += ww;
        }
        float acc = 0.f;
        for (int a = 0; a < nt; ++a) {
            if (wy[a] == 0.f) continue;
            const float* rp = src + (jy0 + a)*WF;
            float rowacc = 0.f;
            for (int bb = 0; bb < nt; ++bb) {
                if (wx[bb] == 0.f) continue;
                rowacc += wx[bb] * rp[jx0 + bb];
            }
            acc += wy[a] * rowacc;
        }
        val = acc / (sy * sx);
    }
    t[idx] = packhl(val * mult);
}

// ---- halo zero: t0 ring (right/bottom) + t1/ra/rb rings (all sides), gated ----
__global__ void haloz_kernel(uint* __restrict__ t0, uint* __restrict__ t1,
                             uint* __restrict__ ra, uint* __restrict__ rb,
                             const float* __restrict__ g, int gi,
                             int h, int w, int h2, int w2) {
    if (g[gi] == 0.0f) return;
    int W1 = w+1, H1 = h+1;
    int idx = blockIdx.x*blockDim.x + threadIdx.x;
    if (idx >= BN*H1*W1) return;
    int px = idx % (H1*W1);
    int b  = idx / (H1*W1);
    int x = px % W1, y = px / W1;
    if (y == h || x == w) {
        uint* p = t0 + ((size_t)b*H1*W1 + px)*40;
        for (int c = 0; c < 40; ++c) p[c] = 0u;
    }
    int W2 = w2+2, H2 = h2+2;
    if (y < H2 && x < W2 && (y == 0 || y == H2-1 || x == 0 || x == W2-1)) {
        size_t o = ((size_t)b*H2*W2 + (size_t)y*W2 + x)*80;
        for (int c = 0; c < 80; ++c) { t1[o+c] = 0u; ra[o+c] = 0u; rb[o+c] = 0u; }
    }
}

// ---- barrier-free packed-NHWC split-bf16 MFMA conv ----
// in/out: packed u32 (hi|lo bf16), channels-last, halo'd buffers, pre-offset to logical (0,0).
// S=1: pad 1 (halo all sides); S=2: pad (0,1) (halo right/bottom).
template<int S, int CIN, int COUT>
__global__ __launch_bounds__(128)
void conv_pk_kernel(const uint* __restrict__ in, int inWP, size_t inBS,
                    const ushort* __restrict__ wt,   // [2][9][COP][KPAD]
                    const float* __restrict__ bias,
                    const uint* __restrict__ resid,  // same geom as out (or null)
                    const float* __restrict__ g, int gi,
                    uint* __restrict__ out, int outWP, size_t outBS,
                    int Hout, int Wout) {
    if (g[gi] == 0.0f) return;
    constexpr int KPAD = ((CIN + 31)/32)*32;
    constexpr int KC   = KPAD/32;
    constexpr int COP  = (COUT == 40) ? 48 : 80;
    constexpr int MS   = COP/16;
    constexpr int PADO = (S == 1) ? 1 : 0;

    int ntx = (Wout + 15)/16;
    int nty = Hout/4;                 // 4 rows per block (2 waves x 2)
    int bx  = blockIdx.x % ntx;
    int t2  = blockIdx.x / ntx;
    int by  = t2 % nty;
    int b   = t2 / nty;

    int lane = threadIdx.x & 63;
    int wave = threadIdx.x >> 6;
    int l15  = lane & 15;
    int l4   = lane >> 4;
    int ox = bx*16 + l15;
    int oyBase = by*4 + wave*2;

    float4v acc[2][MS];
    #pragma unroll
    for (int n = 0; n < 2; ++n)
        #pragma unroll
        for (int m = 0; m < MS; ++m)
            acc[n][m] = (float4v){0.f,0.f,0.f,0.f};

    const uint* inb = in + (size_t)b*inBS;

    #pragma unroll
    for (int kc = 0; kc < KC; ++kc) {
        #pragma unroll
        for (int tap = 0; tap < 9; ++tap) {
            const int dy = tap/3, dx = tap%3;
            short8v bhi[2], blo[2];
            #pragma unroll
            for (int n = 0; n < 2; ++n) {
                int iy = (oyBase + n)*S + dy - PADO;
                int ix = ox*S + dx - PADO;
                const uint* p = inb + ((size_t)iy*inWP + ix)*CIN + (kc*32 + l4*8);
                uint u[8];
                __builtin_memcpy(u, p, 32);
                #pragma unroll
                for (int j = 0; j < 8; ++j) {
                    bhi[n][j] = (short)(u[j] >> 16);
                    blo[n][j] = (short)(u[j] & 0xffffu);
                }
            }
            #pragma unroll
            for (int m = 0; m < MS; ++m) {
                const ushort* wp = wt + ((size_t)(tap*COP + m*16 + l15))*KPAD + kc*32 + l4*8;
                short8v ahi = *(const short8v*)wp;
                short8v alo = *(const short8v*)(wp + (size_t)9*COP*KPAD);
                #pragma unroll
                for (int n = 0; n < 2; ++n) {
                    acc[n][m] = __builtin_amdgcn_mfma_f32_16x16x32_bf16(ahi, bhi[n], acc[n][m], 0, 0, 0);
                    acc[n][m] = __builtin_amdgcn_mfma_f32_16x16x32_bf16(ahi, blo[n], acc[n][m], 0, 0, 0);
                    acc[n][m] = __builtin_amdgcn_mfma_f32_16x16x32_bf16(alo, bhi[n], acc[n][m], 0, 0, 0);
                }
            }
        }
    }

    if (ox < Wout) {
        #pragma unroll
        for (int n = 0; n < 2; ++n) {
            int oy = oyBase + n;
            size_t pbase = (size_t)b*outBS + ((size_t)oy*outWP + ox)*COUT;
            #pragma unroll
            for (int m = 0; m < MS; ++m) {
                #pragma unroll
                for (int r = 0; r < 4; ++r) {
                    int co = m*16 + l4*4 + r;
                    if (co < COUT) {
                        float v = fmaxf(acc[n][m][r] + bias[co], 0.0f);
                        if (resid) v += unpackhl(resid[pbase + co]);
                        out[pbase + co] = packhl(v);
                    }
                }
            }
        }
    }
}

// ---- transposed conv 4x4 s2, packed-NHWC input ----
__global__ void deconv_kernel(const uint* __restrict__ t, int WP, size_t BS,
                              const float* __restrict__ wl,
                              const float* __restrict__ bl,
                              const float* __restrict__ g, int gi,
                              float* __restrict__ out,
                              int h2, int w2) {
    if (g[gi] == 0.0f) return;
    int ho = 2*h2, wo = 2*w2;
    int idx = blockIdx.x * blockDim.x + threadIdx.x;
    int total = BN*5*ho*wo;
    if (idx >= total) return;
    int xx = idx % wo;
    int y  = (idx / wo) % ho;
    int o  = (idx / (wo*ho)) % 5;
    int b  = idx / (wo*ho*5);
    float acc = bl[o];
    int p = y & 1, q = xx & 1;
    const uint* tb = t + (size_t)b*BS;
    for (int dy = 0; dy < 2; ++dy) {
        int ky = p + 2*dy;
        int iy = (y + ky - 2) >> 1;
        if ((unsigned)iy >= (unsigned)h2) continue;
        for (int dx = 0; dx < 2; ++dx) {
            int kx = q + 2*dx;
            int ix = (xx + kx - 2) >> 1;
            if ((unsigned)ix >= (unsigned)w2) continue;
            const uint* tp = tb + ((size_t)iy*WP + ix)*80;
            const float* wp = wl + (size_t)o*80*16 + ky*4 + kx;
            for (int i = 0; i < 80; ++i)
                acc += unpackhl(tp[i]) * wp[i*16];
        }
    }
    out[idx] = acc;
}

// ---- fused: bilinear upsample + gated flow/mask accumulate + backward warp ----
__global__ void upwarp_kernel(const float* __restrict__ tmp,
                              const float* __restrict__ x,
                              const float* __restrict__ g, int gi,
                              float* __restrict__ flow, float* __restrict__ mask,
                              float* __restrict__ w0, float* __restrict__ w1,
                              int h, int w, int f, float fdscale) {
    float gg = g[gi];
    if (gg == 0.0f) return;
    int idx = blockIdx.x * blockDim.x + threadIdx.x;
    if (idx >= BN*HWF) return;
    int p2 = idx % HWF;
    int b  = idx / HWF;
    int xx = p2 % WF, y = p2 / WF;

    float posy = (y + 0.5f)/(float)f - 0.5f;
    float posx = (xx + 0.5f)/(float)f - 0.5f;
    float y0f = floorf(posy), x0f = floorf(posx);
    int jy0 = (int)y0f, jx0 = (int)x0f;
    float fy = posy - y0f, fx = posx - x0f;
    int jy1 = min(jy0 + 1, h-1), jx1 = min(jx0 + 1, w-1);
    jy0 = max(jy0, 0); jx0 = max(jx0, 0);
    float w00 = (1-fx)*(1-fy), w01 = fx*(1-fy), w10 = (1-fx)*fy, w11 = fx*fy;

    float fl[4];
    #pragma unroll
    for (int c = 0; c < 4; ++c) {
        const float* tp = tmp + ((size_t)(b*5 + c))*h*w;
        float val = tp[jy0*w+jx0]*w00 + tp[jy0*w+jx1]*w01 + tp[jy1*w+jx0]*w10 + tp[jy1*w+jx1]*w11;
        size_t fo = ((size_t)b*4 + c)*HWF + p2;
        float nf = flow[fo] + val * fdscale * gg;
        flow[fo] = nf;
        fl[c] = nf;
    }
    {
        const float* tp = tmp + ((size_t)(b*5 + 4))*h*w;
        float val = tp[jy0*w+jx0]*w00 + tp[jy0*w+jx1]*w01 + tp[jy1*w+jx0]*w10 + tp[jy1*w+jx1]*w11;
        mask[(size_t)b*HWF + p2] += val * gg;
    }

    #pragma unroll
    for (int which = 0; which < 2; ++which) {
        float sx = clampf((float)xx + fl[which*2+0], 0.f, (float)(WF-1));
        float sy = clampf((float)y  + fl[which*2+1], 0.f, (float)(HF-1));
        float sx0f = floorf(sx), sy0f = floorf(sy);
        int ix0 = (int)sx0f, iy0 = (int)sy0f;
        int ix1 = min(ix0 + 1, WF - 1), iy1 = min(iy0 + 1, HF - 1);
        float wx = sx - sx0f, wy = sy - sy0f;
        float a00 = (1-wx)*(1-wy), a01 = wx*(1-wy), a10 = (1-wx)*wy, a11 = wx*wy;
        float* dst = which ? w1 : w0;
        #pragma unroll
        for (int c = 0; c < 3; ++c) {
            const float* im = x + ((size_t)b*6 + which*3 + c)*HWF;
            float val = im[iy0*WF+ix0]*a00 + im[iy0*WF+ix1]*a01
                      + im[iy1*WF+ix0]*a10 + im[iy1*WF+ix1]*a11;
            dst[((size_t)b*3 + c)*HWF + p2] = val;
        }
    }
}

// ---- final blend ----
__global__ void final_kernel(const float* __restrict__ w0, const float* __restrict__ w1,
                             const float* __restrict__ mask, float* __restrict__ outp) {
    int idx = blockIdx.x*blockDim.x + threadIdx.x;
    if (idx >= BN*3*HWF) return;
    int p = idx % HWF;
    int b = idx / (3*HWF);
    float m = 1.0f / (1.0f + expf(-mask[(size_t)b*HWF + p]));
    float val = w0[idx]*m + w1[idx]*(1.0f - m);
    outp[idx] = clampf(val, 0.0f, 1.0f);
}

extern "C" void kernel_launch(void* const* d_in, const int* in_sizes, int n_in,
                              void* d_out, int out_size, void* d_ws, size_t ws_size,
                              hipStream_t stream) {
    const float* x     = (const float*)d_in[0];
    const float* wr    = (const float*)d_in[1];
    const float* br    = (const float*)d_in[2];
    const float* wl    = (const float*)d_in[3];
    const float* bl    = (const float*)d_in[4];
    const float* w0a   = (const float*)d_in[5];
    const float* b0a   = (const float*)d_in[6];
    const float* w0b   = (const float*)d_in[7];
    const float* b0b   = (const float*)d_in[8];
    const float* wcb   = (const float*)d_in[9];
    const float* bcb   = (const float*)d_in[10];
    const float* wlast = (const float*)d_in[11];
    const float* blast = (const float*)d_in[12];

    float* ws       = (float*)d_ws;
    double* partial = (double*)d_ws;             // 32*GBLK doubles = 28672 float slots
    float* g        = ws + 28672;                // 16 floats
    size_t off = 28688;
    float* flow = ws + off; off += (size_t)BN*4*HWF;
    float* mask = ws + off; off += (size_t)BN*1*HWF;
    float* wb0  = ws + off; off += (size_t)BN*3*HWF;
    float* wb1  = ws + off; off += (size_t)BN*3*HWF;
    uint*  tinr = (uint*)(ws + off); off += 7900000;           // tin region (max 257*449*17*4 = 7,846,724)
    uint*  t0   = (uint*)(ws + off); off += 4644000;           // 129*225*40*4 = 4,644,000
    float* tmpb = ws + off; off += (size_t)BN*5*(HF/2)*(WF/2);
    ushort* wTa2 = (ushort*)(ws + off); off += (size_t)9*2*9*48*32/2;
    ushort* wTb2 = (ushort*)(ws + off); off += (size_t)9*2*9*80*64/2;
    ushort* wTc2 = (ushort*)(ws + off); off += (size_t)36*2*9*80*96/2;
    // t1/ra/rb alias into tin region (tin dead after convA; each max 4*66*114*80 = 2,407,680)
    uint* t1 = tinr;
    uint* ra = tinr + 2407680;
    uint* rb = tinr + 4815360;

    gate_conv_kernel<<<GBLK, 256, 0, stream>>>(x, wr, br, partial);
    gate_fc_kernel<<<1, 64, 0, stream>>>(partial, wl, bl, g);
    {
        int n = 9*2*9*48*32;
        wprep_kernel<<<(n+255)/256, 256, 0, stream>>>(w0a, wTa2, 9, 40, 17, 48, 32);
        n = 9*2*9*80*64;
        wprep_kernel<<<(n+255)/256, 256, 0, stream>>>(w0b, wTb2, 9, 80, 40, 80, 64);
        n = 36*2*9*80*96;
        wprep_kernel<<<(n+255)/256, 256, 0, stream>>>(wcb, wTc2, 36, 80, 80, 80, 96);
    }
    {
        int n = BN*4*HWF;
        init_kernel<<<(n+255)/256, 256, 0, stream>>>(x, flow, mask, wb0, wb1);
    }
    const int SC[9] = {4,4,4,2,2,2,1,1,1};
    for (int i = 0; i < 9; ++i) {
        int s = SC[i];
        int sh = HF/s, sw = WF/s;
        int h = sh/2, w = sw/2;
        int h2 = h/2, w2 = w/2;
        // geometry (u32 units)
        int tinWP = sw+1;             size_t tinBS = (size_t)(sh+1)*(sw+1)*17;
        int t0WP  = w+1;              size_t t0BS  = (size_t)(h+1)*(w+1)*40;
        int t1WP  = w2+2;             size_t t1BS  = (size_t)(h2+2)*(w2+2)*80;
        size_t ioff = ((size_t)t1WP + 1)*80;   // interior (1,1) offset for S=1 buffers
        {
            int n = BN*(sh+1)*(sw+1)*17;
            prepare_kernel<<<(n+255)/256,256,0,stream>>>(x, wb0, wb1, mask, flow, g, i, tinr, s, sh, sw);
        }
        {   // 17->40 s2
            int ntx = (w + 15)/16, nty = h/4;
            conv_pk_kernel<2,17,40><<<ntx*nty*BN, 128, 0, stream>>>(
                tinr, tinWP, tinBS, wTa2 + (size_t)i*2*9*48*32, b0a + i*40, nullptr,
                g, i, t0, t0WP, t0BS, h, w);
        }
        {   // zero halos of t0 and t1/ra/rb (after convA: tin dead)
            int n = BN*(h+1)*(w+1);
            haloz_kernel<<<(n+255)/256,256,0,stream>>>(t0, t1, ra, rb, g, i, h, w, h2, w2);
        }
        {   // 40->80 s2
            int ntx = (w2 + 15)/16, nty = h2/4;
            conv_pk_kernel<2,40,80><<<ntx*nty*BN, 128, 0, stream>>>(
                t0, t0WP, t0BS, wTb2 + (size_t)i*2*9*80*64, b0b + i*80, nullptr,
                g, i, t1 + ioff, t1WP, t1BS, h2, w2);
        }
        {   // 4x 80->80 s1: t1 -> ra -> rb -> ra -> rb(+resid t1)
            int ntx = (w2 + 15)/16, nty = h2/4;
            int nblk = ntx*nty*BN;
            const uint* cin = t1 + ioff;
            uint* couts[4] = {ra, rb, ra, rb};
            for (int j = 0; j < 4; ++j) {
                const uint* res = (j == 3) ? (t1 + ioff) : nullptr;
                conv_pk_kernel<1,80,80><<<nblk, 128, 0, stream>>>(
                    cin, t1WP, t1BS, wTc2 + ((size_t)i*4 + j)*2*9*80*96, bcb + ((size_t)i*4 + j)*80,
                    res, g, i, couts[j] + ioff, t1WP, t1BS, h2, w2);
                cin = couts[j] + ioff;
            }
        }
        {
            int n = BN*5*h*w;
            deconv_kernel<<<(n+255)/256,256,0,stream>>>(rb + ioff, t1WP, t1BS,
                wlast + (size_t)i*5*80*16, blast + i*5, g, i, tmpb, h2, w2);
        }
        {
            int n = BN*HWF;
            upwarp_kernel<<<(n+255)/256,256,0,stream>>>(tmpb, x, g, i, flow, mask, wb0, wb1,
                h, w, 2*s, (float)(2*s));
        }
    }
    {
        int n = BN*3*HWF;
        final_kernel<<<(n+255)/256,256,0,stream>>>(wb0, wb1, mask, (float*)d_out);
    }
}